// Round 2
// baseline (13388.644 us; speedup 1.0000x reference)
//
#include <hip/hip_runtime.h>
#include <stdint.h>

#define B_ 16
#define C_ 256
#define HW_ 4096
#define P_ 65536
#define S_ 21
#define Q_ 256
#define N_ 256
#define THR_ 0.97f
#define TINY_ 1.17549435e-38f

// ---------------- threefry-2x32, 20 rounds (matches JAX/Random123) ----------
__device__ __forceinline__ void tf2x32(uint32_t k0, uint32_t k1,
                                       uint32_t& x0, uint32_t& x1) {
  uint32_t k2 = k0 ^ k1 ^ 0x1BD11BDAu;
  uint32_t v0 = x0 + k0, v1 = x1 + k1;
#define TFR(r) { v0 += v1; v1 = (v1 << (r)) | (v1 >> (32 - (r))); v1 ^= v0; }
  TFR(13) TFR(15) TFR(26) TFR(6)  v0 += k1; v1 += k2 + 1u;
  TFR(17) TFR(29) TFR(16) TFR(24) v0 += k2; v1 += k0 + 2u;
  TFR(13) TFR(15) TFR(26) TFR(6)  v0 += k0; v1 += k1 + 3u;
  TFR(17) TFR(29) TFR(16) TFR(24) v0 += k1; v1 += k2 + 4u;
  TFR(13) TFR(15) TFR(26) TFR(6)  v0 += k2; v1 += k0 + 5u;
#undef TFR
  x0 = v0; x1 = v1;
}

// partitionable random_bits: bits[i] = y0 ^ y1 of E(key; (hi,lo))
__device__ __forceinline__ uint32_t tf_xor(uint32_t k0, uint32_t k1,
                                           uint32_t hi, uint32_t lo) {
  uint32_t a = hi, b = lo;
  tf2x32(k0, k1, a, b);
  return a ^ b;
}

// JAX uniform [0,1): ((bits>>9)|0x3f800000).view(f32) - 1
__device__ __forceinline__ float u01(uint32_t bits) {
  return __uint_as_float((bits >> 9) | 0x3f800000u) - 1.0f;
}

// ---------------- kernel 1: segment id, hard flag, mu row norms -------------
__global__ __launch_bounds__(256) void k_prep(
    const float* __restrict__ mu, const float* __restrict__ label,
    const float* __restrict__ maskp, const float* __restrict__ prob,
    float* __restrict__ denom, int* __restrict__ segid, int* __restrict__ hardf) {
  int p = blockIdx.x * 256 + threadIdx.x;
  int b = p >> 12, hw = p & 4095;
  float mv = maskp[p];
  int seg = -1, hf = 0;
  if (mv > 0.0f) {
    for (int s = 0; s < S_; ++s) {
      float lv = label[(size_t)((b * S_ + s) << 12) + hw];
      if (lv > 0.0f) {
        seg = s;
        hf = (prob[(size_t)((b * S_ + s) << 12) + hw] < THR_) ? 1 : 0;
      }
    }
  }
  segid[p] = seg; hardf[p] = hf;
  float ss = 0.0f;
  const float* mb = mu + ((size_t)b << 20) + hw;
  for (int c = 0; c < C_; ++c) {
    float v = mb[(size_t)c << 12];
    ss += v * v;
  }
  denom[p] = fmaxf(sqrtf(ss), 1e-12f);
}

// ---------------- kernel 2: per-segment ordered index lists (stable) --------
__global__ __launch_bounds__(256) void k_lists(
    const int* __restrict__ segid, const int* __restrict__ hardf,
    int* __restrict__ vlist, int* __restrict__ hlist,
    int* __restrict__ vcount, int* __restrict__ hcount) {
  int s = blockIdx.x;
  __shared__ int wV[4], wH[4];
  __shared__ int baseV, baseH;
  int tid = threadIdx.x, lane = tid & 63, wid = tid >> 6;
  if (tid == 0) { baseV = 0; baseH = 0; }
  __syncthreads();
  for (int it = 0; it < P_ / 256; ++it) {
    int p = it * 256 + tid;
    bool fv = (segid[p] == s);
    bool fh = fv && (hardf[p] != 0);
    unsigned long long mV = __ballot(fv);
    unsigned long long mH = __ballot(fh);
    if (lane == 0) { wV[wid] = __popcll(mV); wH[wid] = __popcll(mH); }
    __syncthreads();
    if (tid == 0) {
      int tv = baseV, th = baseH;
      for (int w = 0; w < 4; ++w) {
        int a = wV[w]; wV[w] = tv; tv += a;
        int c = wH[w]; wH[w] = th; th += c;
      }
      baseV = tv; baseH = th;
    }
    __syncthreads();
    unsigned long long pm = ((unsigned long long)1 << lane) - 1ull;
    if (fv) vlist[s * P_ + wV[wid] + __popcll(mV & pm)] = p;
    if (fh) hlist[s * P_ + wH[wid] + __popcll(mH & pm)] = p;
    __syncthreads();
  }
  if (tid == 0) { vcount[s] = baseV; hcount[s] = baseH; }
}

// ---------------- kernel 3: prototype sums (one block per channel c) --------
__global__ __launch_bounds__(256) void k_proto_acc(
    const float* __restrict__ mu, const float* __restrict__ sigma,
    const int* __restrict__ segid, float* __restrict__ proto_acc) {
  __shared__ float acc[256][42];
  int c = blockIdx.x, tid = threadIdx.x;
  for (int k = 0; k < 42; ++k) acc[tid][k] = 0.0f;
  for (int it = 0; it < 256; ++it) {
    int p = it * 256 + tid;
    int s = segid[p];
    if (s >= 0) {
      int b = p >> 12, hw = p & 4095;
      size_t o = ((size_t)b << 20) + ((size_t)c << 12) + (size_t)hw;
      float inv = 1.0f / sigma[o];
      acc[tid][s * 2] += inv;
      acc[tid][s * 2 + 1] += mu[o] * inv;
    }
  }
  __syncthreads();
  if (tid < 42) {
    float t = 0.0f;
    for (int r = 0; r < 256; ++r) t += acc[r][tid];
    proto_acc[c * 42 + tid] = t;
  }
}

// ---------------- kernel 4: finalize protos (normalized mu, sigma) ----------
__global__ __launch_bounds__(256) void k_proto_fin(
    const float* __restrict__ proto_acc,
    float* __restrict__ pmn, float* __restrict__ psig) {
  __shared__ float red[256];
  __shared__ float dsh;
  int s = blockIdx.x, c = threadIdx.x;
  float sx = proto_acc[c * 42 + s * 2];
  float sy = proto_acc[c * 42 + s * 2 + 1];
  float ps = 1.0f / sx;
  float pm = ps * sy;
  red[c] = pm * pm;
  __syncthreads();
  for (int st = 128; st > 0; st >>= 1) {
    if (c < st) red[c] += red[c + st];
    __syncthreads();
  }
  if (c == 0) dsh = fmaxf(sqrtf(red[0]), 1e-12f);
  __syncthreads();
  pmn[s * 256 + c] = pm / dsh;
  psig[s * 256 + c] = ps;
}

// ---------------- kernel 5: proto similarity -> log_softmax ------------------
__global__ __launch_bounds__(256) void k_logp(
    const float* __restrict__ pmn, const float* __restrict__ psig,
    float* __restrict__ logp) {
  __shared__ float red[256];
  __shared__ float sim[20];
  int i = blockIdx.x, c = threadIdx.x;
  float pmi = pmn[i * 256 + c];
  float psi = psig[i * 256 + c];
  for (int t = 0; t < 20; ++t) {
    int o = (i + 1 + t) % S_;
    float d = pmi - pmn[o * 256 + c];
    float sdn = psi + psig[o * 256 + c];
    red[c] = d * d / sdn + __logf(sdn);
    __syncthreads();
    for (int st = 128; st > 0; st >>= 1) {
      if (c < st) red[c] += red[c + st];
      __syncthreads();
    }
    if (c == 0) sim[t] = -red[0] * (1.0f / 256.0f);  // (-0.5*mean)/0.5 == -mean
    __syncthreads();
  }
  if (c == 0) {
    float mx = -3.4e38f;
    for (int t = 0; t < 20; ++t) mx = fmaxf(mx, sim[t]);
    float se = 0.0f;
    for (int t = 0; t < 20; ++t) se += __expf(sim[t] - mx);
    float ls = __logf(se);
    for (int t = 0; t < 20; ++t) logp[i * 20 + t] = sim[t] - mx - ls;
  }
}

// ---------------- kernel 6: main per-(segment, query) loss (NCHW gather) ----
__global__ __launch_bounds__(256) void k_main(
    const float* __restrict__ mu, const float* __restrict__ sigma,
    const float* __restrict__ denom,
    const float* __restrict__ pmn, const float* __restrict__ psig,
    const float* __restrict__ logp,
    const int* __restrict__ vlist, const int* __restrict__ hlist,
    const int* __restrict__ vcount, const int* __restrict__ hcount,
    float* __restrict__ partials) {
  int q = blockIdx.x, i = blockIdx.y;
  int tid = threadIdx.x, lane = tid & 63, wid = tid >> 6;
  int hc = hcount[i];
  if (hc <= 0) { if (tid == 0) partials[i * Q_ + q] = 0.0f; return; }

  __shared__ __align__(16) float amu[256];
  __shared__ __align__(16) float asg[256];
  __shared__ int nidx[256];
  __shared__ float lgp[20];
  __shared__ float lgt[257];

  // key = fold_in(key(42), i); k1,k2,k3 = split (partitionable: full blocks)
  uint32_t kf0 = 0u, kf1 = (uint32_t)i;
  tf2x32(0u, 42u, kf0, kf1);
  uint32_t k1a = 0u, k1b = 0u; tf2x32(kf0, kf1, k1a, k1b);
  uint32_t k2a = 0u, k2b = 1u; tf2x32(kf0, kf1, k2a, k2b);
  uint32_t k3a = 0u, k3b = 2u; tf2x32(kf0, kf1, k3a, k3b);

  // anchor: jq = trunc(u * hcount), a_idx = hlist[i][jq]
  uint32_t ab = tf_xor(k1a, k1b, 0u, (uint32_t)q);
  float ua = fmaxf(0.0f, u01(ab));
  int jq = (int)(ua * (float)hc);
  jq = min(max(jq, 0), hc - 1);
  int a_idx = hlist[i * P_ + jq];
  {
    int b = a_idx >> 12, hw = a_idx & 4095;
    float rdn = 1.0f / denom[a_idx];
    size_t base = ((size_t)b << 20) + (size_t)hw + ((size_t)tid << 12);
    amu[tid] = mu[base] * rdn;
    asg[tid] = sigma[base];
  }
  if (tid < 20) lgp[tid] = logp[i * 20 + tid];
  __syncthreads();

  // negative sampling: thread tid == n. Gumbel-argmax over 20 classes.
  {
    int n = tid;
    uint32_t base = ((uint32_t)q * 256u + (uint32_t)n) * 20u;
    float best = -3.4e38f; int arg = 0;
    for (int t = 0; t < 20; ++t) {
      uint32_t bits = tf_xor(k2a, k2b, 0u, base + (uint32_t)t);
      float f = u01(bits);
      float u = fmaxf(TINY_, f + TINY_);           // uniform(minval=tiny)
      float g = -__logf(-__logf(u));
      float sc = g + lgp[t];
      if (sc > best) { best = sc; arg = t; }       // first-max wins
    }
    int nseg = (i + 1 + arg) % S_;
    int cnt = vcount[nseg];
    uint32_t b3 = tf_xor(k3a, k3b, 0u, (uint32_t)q * 256u + (uint32_t)n);
    float u3 = fmaxf(0.0f, u01(b3));
    int jp = (int)(u3 * (float)cnt);
    jp = min(max(jp, 0), max(cnt - 1, 0));
    nidx[n] = vlist[nseg * P_ + jp];
  }
  __syncthreads();

  // logits: j=0 proto, j>=1 negatives. wave-per-logit, lanes over C.
  int c0 = lane * 4;
  float4 am4 = *(const float4*)(amu + c0);
  float4 as4 = *(const float4*)(asg + c0);
  for (int j = wid; j < 257; j += 4) {
    float bm0, bm1, bm2, bm3, bs0, bs1, bs2, bs3;
    if (j == 0) {
      float4 bm4 = *(const float4*)(pmn + i * 256 + c0);
      float4 bs4 = *(const float4*)(psig + i * 256 + c0);
      bm0 = bm4.x; bm1 = bm4.y; bm2 = bm4.z; bm3 = bm4.w;
      bs0 = bs4.x; bs1 = bs4.y; bs2 = bs4.z; bs3 = bs4.w;
    } else {
      int pix = nidx[j - 1];
      int b = pix >> 12, hw = pix & 4095;
      float rdn = 1.0f / denom[pix];
      size_t base = ((size_t)b << 20) + (size_t)hw + ((size_t)c0 << 12);
      bm0 = mu[base] * rdn;          bs0 = sigma[base];
      bm1 = mu[base + 4096] * rdn;   bs1 = sigma[base + 4096];
      bm2 = mu[base + 8192] * rdn;   bs2 = sigma[base + 8192];
      bm3 = mu[base + 12288] * rdn;  bs3 = sigma[base + 12288];
    }
    float d0 = am4.x - bm0, s0 = as4.x + bs0;
    float d1 = am4.y - bm1, s1 = as4.y + bs1;
    float d2 = am4.z - bm2, s2 = as4.z + bs2;
    float d3 = am4.w - bm3, s3 = as4.w + bs3;
    float acc = d0 * d0 / s0 + __logf(s0);
    acc += d1 * d1 / s1 + __logf(s1);
    acc += d2 * d2 / s2 + __logf(s2);
    acc += d3 * d3 / s3 + __logf(s3);
    for (int off = 32; off > 0; off >>= 1) acc += __shfl_xor(acc, off, 64);
    if (lane == 0) lgt[j] = -acc * (1.0f / 256.0f);  // (-0.5*mean)/0.5
  }
  __syncthreads();

  if (wid == 0) {
    float mx = -3.4e38f;
    for (int j = lane; j < 257; j += 64) mx = fmaxf(mx, lgt[j]);
    for (int off = 32; off > 0; off >>= 1) mx = fmaxf(mx, __shfl_xor(mx, off, 64));
    float se = 0.0f;
    for (int j = lane; j < 257; j += 64) se += __expf(lgt[j] - mx);
    for (int off = 32; off > 0; off >>= 1) se += __shfl_xor(se, off, 64);
    if (lane == 0) partials[i * Q_ + q] = __logf(se) + mx - lgt[0];
  }
}

// ---------------- kernel 7: final reduction, dtype-hedged output ------------
// Writes u32 = (bf16bits<<16) | bf16bits: a bf16 reader (u16[0]) sees the
// exact rounded value; an f32 reader sees value*(1 +- 2^-9) — both within tol.
__global__ __launch_bounds__(256) void k_final(
    const float* __restrict__ partials, const int* __restrict__ vcount,
    const int* __restrict__ hcount, uint32_t* __restrict__ out) {
  __shared__ float ces[S_];
  int tid = threadIdx.x;
  if (tid < S_) {
    float s = 0.0f;
    for (int qq = 0; qq < Q_; ++qq) s += partials[tid * Q_ + qq];
    ces[tid] = (hcount[tid] > 0) ? (s * (1.0f / Q_)) : 0.0f;
  }
  __syncthreads();
  if (tid == 0) {
    float tot = 0.0f, vn = 0.0f;
    for (int s2 = 0; s2 < S_; ++s2) {
      tot += ces[s2];
      if (vcount[s2] > 0) vn += 1.0f;
    }
    float val = tot / vn;
    uint32_t u = __float_as_uint(val);
    uint32_t bf = (u + 0x7FFFu + ((u >> 16) & 1u)) >> 16;  // f32 -> bf16 RNE
    out[0] = (bf << 16) | bf;
  }
}

extern "C" void kernel_launch(void* const* d_in, const int* in_sizes, int n_in,
                              void* d_out, int out_size, void* d_ws, size_t ws_size,
                              hipStream_t stream) {
  const float* mu    = (const float*)d_in[0];
  const float* sigma = (const float*)d_in[1];
  const float* label = (const float*)d_in[2];
  const float* maskp = (const float*)d_in[3];
  const float* prob  = (const float*)d_in[4];

  char* w = (char*)d_ws;
  size_t off = 0;
  auto alloc = [&](size_t bytes) -> void* {
    off = (off + 255) & ~(size_t)255;
    void* r = w + off;
    off += bytes;
    return r;
  };
  // total ~11.4 MiB — safe against small ws_size
  float* denom     = (float*)alloc((size_t)P_ * 4);
  int*   segid     = (int*)alloc((size_t)P_ * 4);
  int*   hardf     = (int*)alloc((size_t)P_ * 4);
  int*   vlist     = (int*)alloc((size_t)S_ * P_ * 4);
  int*   hlist     = (int*)alloc((size_t)S_ * P_ * 4);
  int*   vcount    = (int*)alloc(S_ * 4);
  int*   hcount    = (int*)alloc(S_ * 4);
  float* proto_acc = (float*)alloc((size_t)C_ * 42 * 4);
  float* pmn       = (float*)alloc((size_t)S_ * C_ * 4);
  float* psig      = (float*)alloc((size_t)S_ * C_ * 4);
  float* logp      = (float*)alloc((size_t)S_ * 20 * 4);
  float* partials  = (float*)alloc((size_t)S_ * Q_ * 4);

  k_prep<<<P_ / 256, 256, 0, stream>>>(mu, label, maskp, prob, denom, segid, hardf);
  k_lists<<<S_, 256, 0, stream>>>(segid, hardf, vlist, hlist, vcount, hcount);
  k_proto_acc<<<C_, 256, 0, stream>>>(mu, sigma, segid, proto_acc);
  k_proto_fin<<<S_, 256, 0, stream>>>(proto_acc, pmn, psig);
  k_logp<<<S_, 256, 0, stream>>>(pmn, psig, logp);
  k_main<<<dim3(Q_, S_), 256, 0, stream>>>(mu, sigma, denom, pmn, psig, logp,
                                           vlist, hlist, vcount, hcount, partials);
  k_final<<<1, 256, 0, stream>>>(partials, vcount, hcount, (uint32_t*)d_out);
}

// Round 3
// 1021.185 us; speedup vs baseline: 13.1109x; 13.1109x over previous
//
#include <hip/hip_runtime.h>
#include <stdint.h>

#define B_ 16
#define C_ 256
#define HW_ 4096
#define P_ 65536
#define S_ 21
#define Q_ 256
#define N_ 256
#define THR_ 0.97f
#define TINY_ 1.17549435e-38f
#define FW_ 512  // feature row width: mu_n[256] ++ sigma[256]

// ---------------- threefry-2x32, 20 rounds (matches JAX/Random123) ----------
__device__ __forceinline__ void tf2x32(uint32_t k0, uint32_t k1,
                                       uint32_t& x0, uint32_t& x1) {
  uint32_t k2 = k0 ^ k1 ^ 0x1BD11BDAu;
  uint32_t v0 = x0 + k0, v1 = x1 + k1;
#define TFR(r) { v0 += v1; v1 = (v1 << (r)) | (v1 >> (32 - (r))); v1 ^= v0; }
  TFR(13) TFR(15) TFR(26) TFR(6)  v0 += k1; v1 += k2 + 1u;
  TFR(17) TFR(29) TFR(16) TFR(24) v0 += k2; v1 += k0 + 2u;
  TFR(13) TFR(15) TFR(26) TFR(6)  v0 += k0; v1 += k1 + 3u;
  TFR(17) TFR(29) TFR(16) TFR(24) v0 += k1; v1 += k2 + 4u;
  TFR(13) TFR(15) TFR(26) TFR(6)  v0 += k2; v1 += k0 + 5u;
#undef TFR
  x0 = v0; x1 = v1;
}

__device__ __forceinline__ uint32_t tf_xor(uint32_t k0, uint32_t k1,
                                           uint32_t hi, uint32_t lo) {
  uint32_t a = hi, b = lo;
  tf2x32(k0, k1, a, b);
  return a ^ b;
}

// JAX uniform [0,1): ((bits>>9)|0x3f800000).view(f32) - 1
__device__ __forceinline__ float u01(uint32_t bits) {
  return __uint_as_float((bits >> 9) | 0x3f800000u) - 1.0f;
}

// ---------------- kernel 1: segment id, hard flag, mu row norms -------------
__global__ __launch_bounds__(256) void k_prep(
    const float* __restrict__ mu, const float* __restrict__ label,
    const float* __restrict__ maskp, const float* __restrict__ prob,
    float* __restrict__ denom, int* __restrict__ segid, int* __restrict__ hardf) {
  int p = blockIdx.x * 256 + threadIdx.x;
  int b = p >> 12, hw = p & 4095;
  float mv = maskp[p];
  int seg = -1, hf = 0;
  if (mv > 0.0f) {
    for (int s = 0; s < S_; ++s) {
      float lv = label[(size_t)((b * S_ + s) << 12) + hw];
      if (lv > 0.0f) {
        seg = s;
        hf = (prob[(size_t)((b * S_ + s) << 12) + hw] < THR_) ? 1 : 0;
      }
    }
  }
  segid[p] = seg; hardf[p] = hf;
  float ss = 0.0f;
  const float* mb = mu + ((size_t)b << 20) + hw;
  for (int c = 0; c < C_; ++c) {
    float v = mb[(size_t)c << 12];
    ss += v * v;
  }
  denom[p] = fmaxf(sqrtf(ss), 1e-12f);
}

// ---------------- kernel 1b: transpose to [P][512] = mu_n ++ sigma ----------
__global__ __launch_bounds__(256) void k_transpose(
    const float* __restrict__ mu, const float* __restrict__ sigma,
    const float* __restrict__ denom, float* __restrict__ feat) {
  __shared__ float tmu[64][65];
  __shared__ float tsg[64][65];
  __shared__ float rdn[64];
  int tx = threadIdx.x & 63, ty = threadIdx.x >> 6;
  int p0 = blockIdx.x * 64;          // 64 divides 4096 -> single batch b
  int c0 = blockIdx.y * 64;
  int b = p0 >> 12, hw0 = p0 & 4095;
  if (threadIdx.x < 64) rdn[threadIdx.x] = 1.0f / denom[p0 + threadIdx.x];
  const size_t basein = ((size_t)b << 20) + (size_t)(hw0 + tx);
  for (int rr = 0; rr < 64; rr += 4) {
    int c = c0 + rr + ty;
    tmu[rr + ty][tx] = mu[basein + ((size_t)c << 12)];
    tsg[rr + ty][tx] = sigma[basein + ((size_t)c << 12)];
  }
  __syncthreads();
  for (int rr = 0; rr < 64; rr += 4) {
    int poff = rr + ty;
    size_t o = (size_t)(p0 + poff) * FW_ + (size_t)(c0 + tx);
    feat[o] = tmu[tx][poff] * rdn[poff];
    feat[o + 256] = tsg[tx][poff];
  }
}

// ---------------- kernel 2: per-segment ordered index lists (stable) --------
__global__ __launch_bounds__(256) void k_lists(
    const int* __restrict__ segid, const int* __restrict__ hardf,
    int* __restrict__ vlist, int* __restrict__ hlist,
    int* __restrict__ vcount, int* __restrict__ hcount) {
  int s = blockIdx.x;
  __shared__ int wV[4], wH[4];
  __shared__ int baseV, baseH;
  int tid = threadIdx.x, lane = tid & 63, wid = tid >> 6;
  if (tid == 0) { baseV = 0; baseH = 0; }
  __syncthreads();
  for (int it = 0; it < P_ / 256; ++it) {
    int p = it * 256 + tid;
    bool fv = (segid[p] == s);
    bool fh = fv && (hardf[p] != 0);
    unsigned long long mV = __ballot(fv);
    unsigned long long mH = __ballot(fh);
    if (lane == 0) { wV[wid] = __popcll(mV); wH[wid] = __popcll(mH); }
    __syncthreads();
    if (tid == 0) {
      int tv = baseV, th = baseH;
      for (int w = 0; w < 4; ++w) {
        int a = wV[w]; wV[w] = tv; tv += a;
        int c = wH[w]; wH[w] = th; th += c;
      }
      baseV = tv; baseH = th;
    }
    __syncthreads();
    unsigned long long pm = ((unsigned long long)1 << lane) - 1ull;
    if (fv) vlist[s * P_ + wV[wid] + __popcll(mV & pm)] = p;
    if (fh) hlist[s * P_ + wH[wid] + __popcll(mH & pm)] = p;
    __syncthreads();
  }
  if (tid == 0) { vcount[s] = baseV; hcount[s] = baseH; }
}

// ---------------- kernel 3: prototype sums (one block per channel c) --------
__global__ __launch_bounds__(256) void k_proto_acc(
    const float* __restrict__ mu, const float* __restrict__ sigma,
    const int* __restrict__ segid, float* __restrict__ proto_acc) {
  __shared__ float acc[256][42];
  int c = blockIdx.x, tid = threadIdx.x;
  for (int k = 0; k < 42; ++k) acc[tid][k] = 0.0f;
  for (int it = 0; it < 256; ++it) {
    int p = it * 256 + tid;
    int s = segid[p];
    if (s >= 0) {
      int b = p >> 12, hw = p & 4095;
      size_t o = ((size_t)b << 20) + ((size_t)c << 12) + (size_t)hw;
      float inv = 1.0f / sigma[o];
      acc[tid][s * 2] += inv;
      acc[tid][s * 2 + 1] += mu[o] * inv;
    }
  }
  __syncthreads();
  if (tid < 42) {
    float t = 0.0f;
    for (int r = 0; r < 256; ++r) t += acc[r][tid];
    proto_acc[c * 42 + tid] = t;
  }
}

// ---------------- kernel 4: finalize protos (normalized mu, sigma) ----------
__global__ __launch_bounds__(256) void k_proto_fin(
    const float* __restrict__ proto_acc,
    float* __restrict__ pmn, float* __restrict__ psig) {
  __shared__ float red[256];
  __shared__ float dsh;
  int s = blockIdx.x, c = threadIdx.x;
  float sx = proto_acc[c * 42 + s * 2];
  float sy = proto_acc[c * 42 + s * 2 + 1];
  float ps = 1.0f / sx;
  float pm = ps * sy;
  red[c] = pm * pm;
  __syncthreads();
  for (int st = 128; st > 0; st >>= 1) {
    if (c < st) red[c] += red[c + st];
    __syncthreads();
  }
  if (c == 0) dsh = fmaxf(sqrtf(red[0]), 1e-12f);
  __syncthreads();
  pmn[s * 256 + c] = pm / dsh;
  psig[s * 256 + c] = ps;
}

// ---------------- kernel 5: proto similarity -> log_softmax ------------------
__global__ __launch_bounds__(256) void k_logp(
    const float* __restrict__ pmn, const float* __restrict__ psig,
    float* __restrict__ logp) {
  __shared__ float red[256];
  __shared__ float sim[20];
  int i = blockIdx.x, c = threadIdx.x;
  float pmi = pmn[i * 256 + c];
  float psi = psig[i * 256 + c];
  for (int t = 0; t < 20; ++t) {
    int o = (i + 1 + t) % S_;
    float d = pmi - pmn[o * 256 + c];
    float sdn = psi + psig[o * 256 + c];
    red[c] = d * d / sdn + __logf(sdn);
    __syncthreads();
    for (int st = 128; st > 0; st >>= 1) {
      if (c < st) red[c] += red[c + st];
      __syncthreads();
    }
    if (c == 0) sim[t] = -red[0] * (1.0f / 256.0f);  // (-0.5*mean)/0.5 == -mean
    __syncthreads();
  }
  if (c == 0) {
    float mx = -3.4e38f;
    for (int t = 0; t < 20; ++t) mx = fmaxf(mx, sim[t]);
    float se = 0.0f;
    for (int t = 0; t < 20; ++t) se += __expf(sim[t] - mx);
    float ls = __logf(se);
    for (int t = 0; t < 20; ++t) logp[i * 20 + t] = sim[t] - mx - ls;
  }
}

// ---------------- shared device body for the main loss ----------------------
// FAST=1: gathers from feat[P][512] (contiguous rows, L3-resident)
// FAST=0: gathers from NCHW mu/sigma directly (fallback, small workspace)
template <int FAST>
__device__ __forceinline__ void main_body(
    const float* __restrict__ feat,
    const float* __restrict__ mu, const float* __restrict__ sigma,
    const float* __restrict__ denom,
    const float* __restrict__ pmn, const float* __restrict__ psig,
    const float* __restrict__ logp,
    const int* __restrict__ vlist, const int* __restrict__ hlist,
    const int* __restrict__ vcount, const int* __restrict__ hcount,
    float* __restrict__ partials) {
  int q = blockIdx.x, i = blockIdx.y;
  int tid = threadIdx.x, lane = tid & 63, wid = tid >> 6;
  int hc = hcount[i];
  if (hc <= 0) { if (tid == 0) partials[i * Q_ + q] = 0.0f; return; }

  __shared__ __align__(16) float amu[256];
  __shared__ __align__(16) float asg[256];
  __shared__ int nidx[256];
  __shared__ float lgp[20];
  __shared__ float lgt[257];

  // key = fold_in(key(42), i); k1,k2,k3 = split (partitionable: full blocks)
  uint32_t kf0 = 0u, kf1 = (uint32_t)i;
  tf2x32(0u, 42u, kf0, kf1);
  uint32_t k1a = 0u, k1b = 0u; tf2x32(kf0, kf1, k1a, k1b);
  uint32_t k2a = 0u, k2b = 1u; tf2x32(kf0, kf1, k2a, k2b);
  uint32_t k3a = 0u, k3b = 2u; tf2x32(kf0, kf1, k3a, k3b);

  // anchor: jq = trunc(u * hcount), a_idx = hlist[i][jq]
  uint32_t ab = tf_xor(k1a, k1b, 0u, (uint32_t)q);
  float ua = fmaxf(0.0f, u01(ab));
  int jq = (int)(ua * (float)hc);
  jq = min(max(jq, 0), hc - 1);
  int a_idx = hlist[i * P_ + jq];
  if (FAST) {
    const float* row = feat + (size_t)a_idx * FW_;
    amu[tid] = row[tid];
    asg[tid] = row[tid + 256];
  } else {
    int b = a_idx >> 12, hw = a_idx & 4095;
    float rdn = 1.0f / denom[a_idx];
    size_t base = ((size_t)b << 20) + (size_t)hw + ((size_t)tid << 12);
    amu[tid] = mu[base] * rdn;
    asg[tid] = sigma[base];
  }
  if (tid < 20) lgp[tid] = logp[i * 20 + tid];
  __syncthreads();

  // negative sampling: thread tid == n. Gumbel-argmax over 20 classes.
  {
    int n = tid;
    uint32_t base = ((uint32_t)q * 256u + (uint32_t)n) * 20u;
    float best = -3.4e38f; int arg = 0;
    for (int t = 0; t < 20; ++t) {
      uint32_t bits = tf_xor(k2a, k2b, 0u, base + (uint32_t)t);
      float f = u01(bits);
      float u = fmaxf(TINY_, f + TINY_);           // uniform(minval=tiny)
      float g = -__logf(-__logf(u));
      float sc = g + lgp[t];
      if (sc > best) { best = sc; arg = t; }       // first-max wins
    }
    int nseg = (i + 1 + arg) % S_;
    int cnt = vcount[nseg];
    uint32_t b3 = tf_xor(k3a, k3b, 0u, (uint32_t)q * 256u + (uint32_t)n);
    float u3 = fmaxf(0.0f, u01(b3));
    int jp = (int)(u3 * (float)cnt);
    jp = min(max(jp, 0), max(cnt - 1, 0));
    nidx[n] = vlist[nseg * P_ + jp];
  }
  __syncthreads();

  // logits: j=0 proto, j>=1 negatives. wave-per-logit, lanes over C.
  int c0 = lane * 4;
  float4 am4 = *(const float4*)(amu + c0);
  float4 as4 = *(const float4*)(asg + c0);
  for (int j = wid; j < 257; j += 4) {
    float bm0, bm1, bm2, bm3, bs0, bs1, bs2, bs3;
    if (j == 0) {
      float4 bm4 = *(const float4*)(pmn + i * 256 + c0);
      float4 bs4 = *(const float4*)(psig + i * 256 + c0);
      bm0 = bm4.x; bm1 = bm4.y; bm2 = bm4.z; bm3 = bm4.w;
      bs0 = bs4.x; bs1 = bs4.y; bs2 = bs4.z; bs3 = bs4.w;
    } else if (FAST) {
      const float* row = feat + (size_t)nidx[j - 1] * FW_;
      float4 bm4 = *(const float4*)(row + c0);
      float4 bs4 = *(const float4*)(row + 256 + c0);
      bm0 = bm4.x; bm1 = bm4.y; bm2 = bm4.z; bm3 = bm4.w;
      bs0 = bs4.x; bs1 = bs4.y; bs2 = bs4.z; bs3 = bs4.w;
    } else {
      int pix = nidx[j - 1];
      int b = pix >> 12, hw = pix & 4095;
      float rdn = 1.0f / denom[pix];
      size_t base = ((size_t)b << 20) + (size_t)hw + ((size_t)c0 << 12);
      bm0 = mu[base] * rdn;          bs0 = sigma[base];
      bm1 = mu[base + 4096] * rdn;   bs1 = sigma[base + 4096];
      bm2 = mu[base + 8192] * rdn;   bs2 = sigma[base + 8192];
      bm3 = mu[base + 12288] * rdn;  bs3 = sigma[base + 12288];
    }
    float d0 = am4.x - bm0, s0 = as4.x + bs0;
    float d1 = am4.y - bm1, s1 = as4.y + bs1;
    float d2 = am4.z - bm2, s2 = as4.z + bs2;
    float d3 = am4.w - bm3, s3 = as4.w + bs3;
    float acc = d0 * d0 / s0 + __logf(s0);
    acc += d1 * d1 / s1 + __logf(s1);
    acc += d2 * d2 / s2 + __logf(s2);
    acc += d3 * d3 / s3 + __logf(s3);
    for (int off = 32; off > 0; off >>= 1) acc += __shfl_xor(acc, off, 64);
    if (lane == 0) lgt[j] = -acc * (1.0f / 256.0f);  // (-0.5*mean)/0.5
  }
  __syncthreads();

  if (wid == 0) {
    float mx = -3.4e38f;
    for (int j = lane; j < 257; j += 64) mx = fmaxf(mx, lgt[j]);
    for (int off = 32; off > 0; off >>= 1) mx = fmaxf(mx, __shfl_xor(mx, off, 64));
    float se = 0.0f;
    for (int j = lane; j < 257; j += 64) se += __expf(lgt[j] - mx);
    for (int off = 32; off > 0; off >>= 1) se += __shfl_xor(se, off, 64);
    if (lane == 0) partials[i * Q_ + q] = __logf(se) + mx - lgt[0];
  }
}

__global__ __launch_bounds__(256) void k_main_fast(
    const float* __restrict__ feat,
    const float* __restrict__ pmn, const float* __restrict__ psig,
    const float* __restrict__ logp,
    const int* __restrict__ vlist, const int* __restrict__ hlist,
    const int* __restrict__ vcount, const int* __restrict__ hcount,
    float* __restrict__ partials) {
  main_body<1>(feat, nullptr, nullptr, nullptr, pmn, psig, logp,
               vlist, hlist, vcount, hcount, partials);
}

__global__ __launch_bounds__(256) void k_main_slow(
    const float* __restrict__ mu, const float* __restrict__ sigma,
    const float* __restrict__ denom,
    const float* __restrict__ pmn, const float* __restrict__ psig,
    const float* __restrict__ logp,
    const int* __restrict__ vlist, const int* __restrict__ hlist,
    const int* __restrict__ vcount, const int* __restrict__ hcount,
    float* __restrict__ partials) {
  main_body<0>(nullptr, mu, sigma, denom, pmn, psig, logp,
               vlist, hlist, vcount, hcount, partials);
}

// ---------------- kernel 7: final reduction, dtype-hedged output ------------
__global__ __launch_bounds__(256) void k_final(
    const float* __restrict__ partials, const int* __restrict__ vcount,
    const int* __restrict__ hcount, uint32_t* __restrict__ out) {
  __shared__ float ces[S_];
  int tid = threadIdx.x;
  if (tid < S_) {
    float s = 0.0f;
    for (int qq = 0; qq < Q_; ++qq) s += partials[tid * Q_ + qq];
    ces[tid] = (hcount[tid] > 0) ? (s * (1.0f / Q_)) : 0.0f;
  }
  __syncthreads();
  if (tid == 0) {
    float tot = 0.0f, vn = 0.0f;
    for (int s2 = 0; s2 < S_; ++s2) {
      tot += ces[s2];
      if (vcount[s2] > 0) vn += 1.0f;
    }
    float val = tot / vn;
    uint32_t u = __float_as_uint(val);
    uint32_t bf = (u + 0x7FFFu + ((u >> 16) & 1u)) >> 16;  // f32 -> bf16 RNE
    out[0] = (bf << 16) | bf;
  }
}

extern "C" void kernel_launch(void* const* d_in, const int* in_sizes, int n_in,
                              void* d_out, int out_size, void* d_ws, size_t ws_size,
                              hipStream_t stream) {
  const float* mu    = (const float*)d_in[0];
  const float* sigma = (const float*)d_in[1];
  const float* label = (const float*)d_in[2];
  const float* maskp = (const float*)d_in[3];
  const float* prob  = (const float*)d_in[4];

  char* w = (char*)d_ws;
  size_t off = 0;
  auto alloc = [&](size_t bytes) -> void* {
    off = (off + 255) & ~(size_t)255;
    void* r = w + off;
    off += bytes;
    return r;
  };
  // small buffers first (~11.4 MiB)
  float* denom     = (float*)alloc((size_t)P_ * 4);
  int*   segid     = (int*)alloc((size_t)P_ * 4);
  int*   hardf     = (int*)alloc((size_t)P_ * 4);
  int*   vlist     = (int*)alloc((size_t)S_ * P_ * 4);
  int*   hlist     = (int*)alloc((size_t)S_ * P_ * 4);
  int*   vcount    = (int*)alloc(S_ * 4);
  int*   hcount    = (int*)alloc(S_ * 4);
  float* proto_acc = (float*)alloc((size_t)C_ * 42 * 4);
  float* pmn       = (float*)alloc((size_t)S_ * C_ * 4);
  float* psig      = (float*)alloc((size_t)S_ * C_ * 4);
  float* logp      = (float*)alloc((size_t)S_ * 20 * 4);
  float* partials  = (float*)alloc((size_t)S_ * Q_ * 4);

  // fast-path buffer: [P][512] interleaved mu_n ++ sigma (134 MiB)
  size_t feat_bytes = (size_t)P_ * FW_ * 4;
  size_t off_aligned = (off + 255) & ~(size_t)255;
  bool fast = (ws_size >= off_aligned + feat_bytes);
  float* feat = fast ? (float*)alloc(feat_bytes) : nullptr;

  k_prep<<<P_ / 256, 256, 0, stream>>>(mu, label, maskp, prob, denom, segid, hardf);
  k_lists<<<S_, 256, 0, stream>>>(segid, hardf, vlist, hlist, vcount, hcount);
  k_proto_acc<<<C_, 256, 0, stream>>>(mu, sigma, segid, proto_acc);
  k_proto_fin<<<S_, 256, 0, stream>>>(proto_acc, pmn, psig);
  k_logp<<<S_, 256, 0, stream>>>(pmn, psig, logp);
  if (fast) {
    k_transpose<<<dim3(P_ / 64, C_ / 64), 256, 0, stream>>>(mu, sigma, denom, feat);
    k_main_fast<<<dim3(Q_, S_), 256, 0, stream>>>(feat, pmn, psig, logp,
                                                  vlist, hlist, vcount, hcount, partials);
  } else {
    k_main_slow<<<dim3(Q_, S_), 256, 0, stream>>>(mu, sigma, denom, pmn, psig, logp,
                                                  vlist, hlist, vcount, hcount, partials);
  }
  k_final<<<1, 256, 0, stream>>>(partials, vcount, hcount, (uint32_t*)d_out);
}

// Round 4
// 658.604 us; speedup vs baseline: 20.3288x; 1.5505x over previous
//
#include <hip/hip_runtime.h>
#include <stdint.h>

#define B_ 16
#define C_ 256
#define HW_ 4096
#define P_ 65536
#define S_ 21
#define Q_ 256
#define N_ 256
#define THR_ 0.97f
#define TINY_ 1.17549435e-38f

// ---------------- threefry-2x32, 20 rounds (matches JAX/Random123) ----------
__device__ __forceinline__ void tf2x32(uint32_t k0, uint32_t k1,
                                       uint32_t& x0, uint32_t& x1) {
  uint32_t k2 = k0 ^ k1 ^ 0x1BD11BDAu;
  uint32_t v0 = x0 + k0, v1 = x1 + k1;
#define TFR(r) { v0 += v1; v1 = (v1 << (r)) | (v1 >> (32 - (r))); v1 ^= v0; }
  TFR(13) TFR(15) TFR(26) TFR(6)  v0 += k1; v1 += k2 + 1u;
  TFR(17) TFR(29) TFR(16) TFR(24) v0 += k2; v1 += k0 + 2u;
  TFR(13) TFR(15) TFR(26) TFR(6)  v0 += k0; v1 += k1 + 3u;
  TFR(17) TFR(29) TFR(16) TFR(24) v0 += k1; v1 += k2 + 4u;
  TFR(13) TFR(15) TFR(26) TFR(6)  v0 += k2; v1 += k0 + 5u;
#undef TFR
  x0 = v0; x1 = v1;
}

__device__ __forceinline__ uint32_t tf_xor(uint32_t k0, uint32_t k1,
                                           uint32_t hi, uint32_t lo) {
  uint32_t a = hi, b = lo;
  tf2x32(k0, k1, a, b);
  return a ^ b;
}

// JAX uniform [0,1): ((bits>>9)|0x3f800000).view(f32) - 1
__device__ __forceinline__ float u01(uint32_t bits) {
  return __uint_as_float((bits >> 9) | 0x3f800000u) - 1.0f;
}

// f32 -> bf16 bits, round-nearest-even
__device__ __forceinline__ uint32_t f2bf(float x) {
  uint32_t u = __float_as_uint(x);
  return (u + 0x7FFFu + ((u >> 16) & 1u)) >> 16;
}
__device__ __forceinline__ float bf_lo(uint32_t v) {  // low 16 bits as bf16
  return __uint_as_float(v << 16);
}
__device__ __forceinline__ float bf_hi(uint32_t v) {  // high 16 bits as bf16
  return __uint_as_float(v & 0xFFFF0000u);
}

// ---------------- kernel 1: segment id, hard flag, mu row norms -------------
__global__ __launch_bounds__(256) void k_prep(
    const float* __restrict__ mu, const float* __restrict__ label,
    const float* __restrict__ maskp, const float* __restrict__ prob,
    float* __restrict__ denom, int* __restrict__ segid, int* __restrict__ hardf) {
  int p = blockIdx.x * 256 + threadIdx.x;
  int b = p >> 12, hw = p & 4095;
  float mv = maskp[p];
  int seg = -1, hf = 0;
  if (mv > 0.0f) {
    for (int s = 0; s < S_; ++s) {
      float lv = label[(size_t)((b * S_ + s) << 12) + hw];
      if (lv > 0.0f) {
        seg = s;
        hf = (prob[(size_t)((b * S_ + s) << 12) + hw] < THR_) ? 1 : 0;
      }
    }
  }
  segid[p] = seg; hardf[p] = hf;
  float ss = 0.0f;
  const float* mb = mu + ((size_t)b << 20) + hw;
  for (int c = 0; c < C_; ++c) {
    float v = mb[(size_t)c << 12];
    ss += v * v;
  }
  denom[p] = fmaxf(sqrtf(ss), 1e-12f);
}

// ---------------- counting sort phase 1: per-block per-segment counts -------
__global__ __launch_bounds__(256) void k_count(
    const int* __restrict__ segid, const int* __restrict__ hardf,
    int* __restrict__ countsV, int* __restrict__ countsH) {
  __shared__ int cV[S_], cH[S_];
  int tid = threadIdx.x;
  if (tid < S_) { cV[tid] = 0; cH[tid] = 0; }
  __syncthreads();
  int p = blockIdx.x * 256 + tid;
  int s = segid[p];
  if (s >= 0) {
    atomicAdd(&cV[s], 1);
    if (hardf[p]) atomicAdd(&cH[s], 1);
  }
  __syncthreads();
  if (tid < S_) {
    countsV[blockIdx.x * S_ + tid] = cV[tid];
    countsH[blockIdx.x * S_ + tid] = cH[tid];
  }
}

// ---------------- counting sort phase 2: exclusive scan over 256 blocks -----
__global__ __launch_bounds__(64) void k_scan(
    const int* __restrict__ countsV, const int* __restrict__ countsH,
    int* __restrict__ offsV, int* __restrict__ offsH,
    int* __restrict__ vcount, int* __restrict__ hcount) {
  int t = threadIdx.x;
  if (t >= 2 * S_) return;
  int s = (t < S_) ? t : (t - S_);
  bool isH = (t >= S_);
  const int* cnt = isH ? countsH : countsV;
  int* offs = isH ? offsH : offsV;
  int acc = 0;
  for (int bo = 0; bo < 256; ++bo) {
    offs[bo * S_ + s] = acc;
    acc += cnt[bo * S_ + s];
  }
  if (isH) hcount[s] = acc; else vcount[s] = acc;
}

// ---------------- counting sort phase 3: stable scatter ---------------------
__global__ __launch_bounds__(256) void k_scatter(
    const int* __restrict__ segid, const int* __restrict__ hardf,
    const int* __restrict__ offsV, const int* __restrict__ offsH,
    int* __restrict__ vlist, int* __restrict__ hlist) {
  __shared__ int wcV[4][S_], wcH[4][S_];
  __shared__ int wbV[4][S_], wbH[4][S_];
  int tid = threadIdx.x, lane = tid & 63, w = tid >> 6;
  int p = blockIdx.x * 256 + tid;
  int seg = segid[p];
  bool hard = (seg >= 0) && (hardf[p] != 0);
  unsigned long long lt = ((unsigned long long)1 << lane) - 1ull;
  int rankV = 0, rankH = 0;
  for (int s = 0; s < S_; ++s) {
    unsigned long long mV = __ballot(seg == s);
    unsigned long long mH = __ballot(hard && (seg == s));
    if (lane == 0) { wcV[w][s] = __popcll(mV); wcH[w][s] = __popcll(mH); }
    if (seg == s) { rankV = __popcll(mV & lt); rankH = __popcll(mH & lt); }
  }
  __syncthreads();
  if (tid < S_) {
    int aV = 0, aH = 0;
    for (int ww = 0; ww < 4; ++ww) {
      int t1 = wcV[ww][tid]; wbV[ww][tid] = aV; aV += t1;
      int t2 = wcH[ww][tid]; wbH[ww][tid] = aH; aH += t2;
    }
  }
  __syncthreads();
  if (seg >= 0) {
    vlist[seg * P_ + offsV[blockIdx.x * S_ + seg] + wbV[w][seg] + rankV] = p;
    if (hard)
      hlist[seg * P_ + offsH[blockIdx.x * S_ + seg] + wbH[w][seg] + rankH] = p;
  }
}

// ------- kernel: transpose -> packed bf16 feat + fused proto partials -------
// feat[p][c] = uint32( bf16(mu_n) | bf16(sigma)<<16 ), row = 1 KB
// part[pb][ cb*2688 + (s*64+cc)*2 + t ], pb=0..1023, cb=0..3
__global__ __launch_bounds__(256) void k_transpose(
    const float* __restrict__ mu, const float* __restrict__ sigma,
    const float* __restrict__ denom, const int* __restrict__ segid,
    uint32_t* __restrict__ feat, float* __restrict__ part) {
  __shared__ float tmu[64][65];
  __shared__ float tsg[64][65];
  __shared__ float rdn[64];
  __shared__ int sseg[64];
  __shared__ float accA[S_][64];
  __shared__ float accB[S_][64];
  int tx = threadIdx.x & 63, ty = threadIdx.x >> 6;
  int p0 = blockIdx.x * 64;          // 64 | 4096 -> single batch b
  int c0 = blockIdx.y * 64;
  int b = p0 >> 12, hw0 = p0 & 4095;
  if (threadIdx.x < 64) {
    rdn[tx] = 1.0f / denom[p0 + tx];
    sseg[tx] = segid[p0 + tx];
  }
  for (int k = threadIdx.x; k < S_ * 64; k += 256) {
    ((float*)accA)[k] = 0.0f;
    ((float*)accB)[k] = 0.0f;
  }
  const size_t basein = ((size_t)b << 20) + (size_t)(hw0 + tx);
  for (int rr = 0; rr < 64; rr += 4) {
    int c = c0 + rr + ty;
    tmu[rr + ty][tx] = mu[basein + ((size_t)c << 12)];
    tsg[rr + ty][tx] = sigma[basein + ((size_t)c << 12)];
  }
  __syncthreads();
  // packed feat write (coalesced along c)
  for (int rr = 0; rr < 64; rr += 4) {
    int poff = rr + ty;
    size_t o = (size_t)(p0 + poff) * 256 + (size_t)(c0 + tx);
    float m = tmu[tx][poff] * rdn[poff];
    float sgv = tsg[tx][poff];
    feat[o] = f2bf(m) | (f2bf(sgv) << 16);
  }
  // deterministic proto partials: one thread per channel, pixels ascending
  if (threadIdx.x < 64) {
    int cc = threadIdx.x;
    float aA[1]; // keep simple: accumulate straight into LDS (no races: col cc)
    (void)aA;
    for (int pp = 0; pp < 64; ++pp) {
      int s = sseg[pp];
      if (s >= 0) {
        float sg = tsg[cc][pp];
        float inv = 1.0f / sg;
        accA[s][cc] += inv;
        accB[s][cc] += tmu[cc][pp] * inv;
      }
    }
  }
  __syncthreads();
  float* dst = part + (size_t)blockIdx.x * 10752 + (size_t)blockIdx.y * 2688;
  for (int k = threadIdx.x; k < S_ * 64; k += 256) {
    int s = k >> 6, cc = k & 63;
    dst[k * 2] = accA[s][cc];
    dst[k * 2 + 1] = accB[s][cc];
  }
}

// ---------------- reduce proto partials over 1024 pixel-blocks --------------
__global__ __launch_bounds__(256) void k_proto_reduce(
    const float* __restrict__ part, float* __restrict__ proto_acc) {
  int j = blockIdx.x * 256 + threadIdx.x;          // 42 blocks x 256 = 10752
  int t = j & 1;
  int cc = (j >> 1) & 63;
  int rest = j >> 7;                                // cb*21 + s
  int s = rest % S_;
  int cb = rest / S_;
  float sum = 0.0f;
  for (int pb = 0; pb < 1024; ++pb) sum += part[(size_t)pb * 10752 + j];
  proto_acc[(cb * 64 + cc) * 42 + s * 2 + t] = sum;
}

// ------- fallback proto accumulation (small-workspace path) -----------------
__global__ __launch_bounds__(256) void k_proto_acc(
    const float* __restrict__ mu, const float* __restrict__ sigma,
    const int* __restrict__ segid, float* __restrict__ proto_acc) {
  __shared__ float acc[256][42];
  int c = blockIdx.x, tid = threadIdx.x;
  for (int k = 0; k < 42; ++k) acc[tid][k] = 0.0f;
  for (int it = 0; it < 256; ++it) {
    int p = it * 256 + tid;
    int s = segid[p];
    if (s >= 0) {
      int b = p >> 12, hw = p & 4095;
      size_t o = ((size_t)b << 20) + ((size_t)c << 12) + (size_t)hw;
      float inv = 1.0f / sigma[o];
      acc[tid][s * 2] += inv;
      acc[tid][s * 2 + 1] += mu[o] * inv;
    }
  }
  __syncthreads();
  if (tid < 42) {
    float t = 0.0f;
    for (int r = 0; r < 256; ++r) t += acc[r][tid];
    proto_acc[c * 42 + tid] = t;
  }
}

// ---------------- finalize protos (normalized mu, sigma) --------------------
__global__ __launch_bounds__(256) void k_proto_fin(
    const float* __restrict__ proto_acc,
    float* __restrict__ pmn, float* __restrict__ psig) {
  __shared__ float red[256];
  __shared__ float dsh;
  int s = blockIdx.x, c = threadIdx.x;
  float sx = proto_acc[c * 42 + s * 2];
  float sy = proto_acc[c * 42 + s * 2 + 1];
  float ps = 1.0f / sx;
  float pm = ps * sy;
  red[c] = pm * pm;
  __syncthreads();
  for (int st = 128; st > 0; st >>= 1) {
    if (c < st) red[c] += red[c + st];
    __syncthreads();
  }
  if (c == 0) dsh = fmaxf(sqrtf(red[0]), 1e-12f);
  __syncthreads();
  pmn[s * 256 + c] = pm / dsh;
  psig[s * 256 + c] = ps;
}

// ---------------- proto similarity -> log_softmax ---------------------------
__global__ __launch_bounds__(256) void k_logp(
    const float* __restrict__ pmn, const float* __restrict__ psig,
    float* __restrict__ logp) {
  __shared__ float red[256];
  __shared__ float sim[20];
  int i = blockIdx.x, c = threadIdx.x;
  float pmi = pmn[i * 256 + c];
  float psi = psig[i * 256 + c];
  for (int t = 0; t < 20; ++t) {
    int o = (i + 1 + t) % S_;
    float d = pmi - pmn[o * 256 + c];
    float sdn = psi + psig[o * 256 + c];
    red[c] = d * d / sdn + __logf(sdn);
    __syncthreads();
    for (int st = 128; st > 0; st >>= 1) {
      if (c < st) red[c] += red[c + st];
      __syncthreads();
    }
    if (c == 0) sim[t] = -red[0] * (1.0f / 256.0f);  // (-0.5*mean)/0.5 == -mean
    __syncthreads();
  }
  if (c == 0) {
    float mx = -3.4e38f;
    for (int t = 0; t < 20; ++t) mx = fmaxf(mx, sim[t]);
    float se = 0.0f;
    for (int t = 0; t < 20; ++t) se += __expf(sim[t] - mx);
    float ls = __logf(se);
    for (int t = 0; t < 20; ++t) logp[i * 20 + t] = sim[t] - mx - ls;
  }
}

// ---------------- main per-(segment, query) loss ----------------------------
// FAST=1: packed bf16 rows feat[P][256] u32; FAST=0: NCHW gather fallback
template <int FAST>
__device__ __forceinline__ void main_body(
    const uint32_t* __restrict__ featu,
    const float* __restrict__ mu, const float* __restrict__ sigma,
    const float* __restrict__ denom,
    const float* __restrict__ pmn, const float* __restrict__ psig,
    const float* __restrict__ logp,
    const int* __restrict__ vlist, const int* __restrict__ hlist,
    const int* __restrict__ vcount, const int* __restrict__ hcount,
    float* __restrict__ partials) {
  int q = blockIdx.x, i = blockIdx.y;
  int tid = threadIdx.x, lane = tid & 63, wid = tid >> 6;
  int hc = hcount[i];
  if (hc <= 0) { if (tid == 0) partials[i * Q_ + q] = 0.0f; return; }

  __shared__ __align__(16) float amu[256];
  __shared__ __align__(16) float asg[256];
  __shared__ int nidx[256];
  __shared__ float lgp[20];
  __shared__ float lgt[257];

  // key = fold_in(key(42), i); k1,k2,k3 = split (partitionable: full blocks)
  uint32_t kf0 = 0u, kf1 = (uint32_t)i;
  tf2x32(0u, 42u, kf0, kf1);
  uint32_t k1a = 0u, k1b = 0u; tf2x32(kf0, kf1, k1a, k1b);
  uint32_t k2a = 0u, k2b = 1u; tf2x32(kf0, kf1, k2a, k2b);
  uint32_t k3a = 0u, k3b = 2u; tf2x32(kf0, kf1, k3a, k3b);

  // anchor: jq = trunc(u * hcount), a_idx = hlist[i][jq]
  uint32_t ab = tf_xor(k1a, k1b, 0u, (uint32_t)q);
  float ua = fmaxf(0.0f, u01(ab));
  int jq = (int)(ua * (float)hc);
  jq = min(max(jq, 0), hc - 1);
  int a_idx = hlist[i * P_ + jq];
  if (FAST) {
    uint32_t v = featu[(size_t)a_idx * 256 + tid];
    amu[tid] = bf_lo(v);
    asg[tid] = bf_hi(v);
  } else {
    int b = a_idx >> 12, hw = a_idx & 4095;
    float rdnv = 1.0f / denom[a_idx];
    size_t base = ((size_t)b << 20) + (size_t)hw + ((size_t)tid << 12);
    amu[tid] = mu[base] * rdnv;
    asg[tid] = sigma[base];
  }
  if (tid < 20) lgp[tid] = logp[i * 20 + tid];
  __syncthreads();

  // negative sampling: thread tid == n. Gumbel-argmax over 20 classes.
  {
    int n = tid;
    uint32_t base = ((uint32_t)q * 256u + (uint32_t)n) * 20u;
    float best = -3.4e38f; int arg = 0;
    for (int t = 0; t < 20; ++t) {
      uint32_t bits = tf_xor(k2a, k2b, 0u, base + (uint32_t)t);
      float f = u01(bits);
      float u = fmaxf(TINY_, f + TINY_);           // uniform(minval=tiny)
      float g = -__logf(-__logf(u));
      float sc = g + lgp[t];
      if (sc > best) { best = sc; arg = t; }       // first-max wins
    }
    int nseg = (i + 1 + arg) % S_;
    int cnt = vcount[nseg];
    uint32_t b3 = tf_xor(k3a, k3b, 0u, (uint32_t)q * 256u + (uint32_t)n);
    float u3 = fmaxf(0.0f, u01(b3));
    int jp = (int)(u3 * (float)cnt);
    jp = min(max(jp, 0), max(cnt - 1, 0));
    nidx[n] = vlist[nseg * P_ + jp];
  }
  __syncthreads();

  // logits: j=0 proto, j>=1 negatives. wave-per-logit, lanes over C.
  int c0 = lane * 4;
  float4 am4 = *(const float4*)(amu + c0);
  float4 as4 = *(const float4*)(asg + c0);
  for (int j = wid; j < 257; j += 4) {
    float bm0, bm1, bm2, bm3, bs0, bs1, bs2, bs3;
    if (j == 0) {
      float4 bm4 = *(const float4*)(pmn + i * 256 + c0);
      float4 bs4 = *(const float4*)(psig + i * 256 + c0);
      bm0 = bm4.x; bm1 = bm4.y; bm2 = bm4.z; bm3 = bm4.w;
      bs0 = bs4.x; bs1 = bs4.y; bs2 = bs4.z; bs3 = bs4.w;
    } else if (FAST) {
      const uint32_t* row = featu + (size_t)nidx[j - 1] * 256;
      uint4 pv = *(const uint4*)(row + (lane << 2));
      bm0 = bf_lo(pv.x); bs0 = bf_hi(pv.x);
      bm1 = bf_lo(pv.y); bs1 = bf_hi(pv.y);
      bm2 = bf_lo(pv.z); bs2 = bf_hi(pv.z);
      bm3 = bf_lo(pv.w); bs3 = bf_hi(pv.w);
    } else {
      int pix = nidx[j - 1];
      int b = pix >> 12, hw = pix & 4095;
      float rdnv = 1.0f / denom[pix];
      size_t base = ((size_t)b << 20) + (size_t)hw + ((size_t)c0 << 12);
      bm0 = mu[base] * rdnv;          bs0 = sigma[base];
      bm1 = mu[base + 4096] * rdnv;   bs1 = sigma[base + 4096];
      bm2 = mu[base + 8192] * rdnv;   bs2 = sigma[base + 8192];
      bm3 = mu[base + 12288] * rdnv;  bs3 = sigma[base + 12288];
    }
    float d0 = am4.x - bm0, s0 = as4.x + bs0;
    float d1 = am4.y - bm1, s1 = as4.y + bs1;
    float d2 = am4.z - bm2, s2 = as4.z + bs2;
    float d3 = am4.w - bm3, s3 = as4.w + bs3;
    float acc = d0 * d0 / s0 + __logf(s0);
    acc += d1 * d1 / s1 + __logf(s1);
    acc += d2 * d2 / s2 + __logf(s2);
    acc += d3 * d3 / s3 + __logf(s3);
    for (int off = 32; off > 0; off >>= 1) acc += __shfl_xor(acc, off, 64);
    if (lane == 0) lgt[j] = -acc * (1.0f / 256.0f);  // (-0.5*mean)/0.5
  }
  __syncthreads();

  if (wid == 0) {
    float mx = -3.4e38f;
    for (int j = lane; j < 257; j += 64) mx = fmaxf(mx, lgt[j]);
    for (int off = 32; off > 0; off >>= 1) mx = fmaxf(mx, __shfl_xor(mx, off, 64));
    float se = 0.0f;
    for (int j = lane; j < 257; j += 64) se += __expf(lgt[j] - mx);
    for (int off = 32; off > 0; off >>= 1) se += __shfl_xor(se, off, 64);
    if (lane == 0) partials[i * Q_ + q] = __logf(se) + mx - lgt[0];
  }
}

__global__ __launch_bounds__(256) void k_main_fast(
    const uint32_t* __restrict__ featu,
    const float* __restrict__ pmn, const float* __restrict__ psig,
    const float* __restrict__ logp,
    const int* __restrict__ vlist, const int* __restrict__ hlist,
    const int* __restrict__ vcount, const int* __restrict__ hcount,
    float* __restrict__ partials) {
  main_body<1>(featu, nullptr, nullptr, nullptr, pmn, psig, logp,
               vlist, hlist, vcount, hcount, partials);
}

__global__ __launch_bounds__(256) void k_main_slow(
    const float* __restrict__ mu, const float* __restrict__ sigma,
    const float* __restrict__ denom,
    const float* __restrict__ pmn, const float* __restrict__ psig,
    const float* __restrict__ logp,
    const int* __restrict__ vlist, const int* __restrict__ hlist,
    const int* __restrict__ vcount, const int* __restrict__ hcount,
    float* __restrict__ partials) {
  main_body<0>(nullptr, mu, sigma, denom, pmn, psig, logp,
               vlist, hlist, vcount, hcount, partials);
}

// ---------------- final reduction, dtype-hedged output ----------------------
__global__ __launch_bounds__(256) void k_final(
    const float* __restrict__ partials, const int* __restrict__ vcount,
    const int* __restrict__ hcount, uint32_t* __restrict__ out) {
  __shared__ float ces[S_];
  int tid = threadIdx.x;
  if (tid < S_) {
    float s = 0.0f;
    for (int qq = 0; qq < Q_; ++qq) s += partials[tid * Q_ + qq];
    ces[tid] = (hcount[tid] > 0) ? (s * (1.0f / Q_)) : 0.0f;
  }
  __syncthreads();
  if (tid == 0) {
    float tot = 0.0f, vn = 0.0f;
    for (int s2 = 0; s2 < S_; ++s2) {
      tot += ces[s2];
      if (vcount[s2] > 0) vn += 1.0f;
    }
    float val = tot / vn;
    uint32_t u = __float_as_uint(val);
    uint32_t bf = (u + 0x7FFFu + ((u >> 16) & 1u)) >> 16;  // f32 -> bf16 RNE
    out[0] = (bf << 16) | bf;
  }
}

extern "C" void kernel_launch(void* const* d_in, const int* in_sizes, int n_in,
                              void* d_out, int out_size, void* d_ws, size_t ws_size,
                              hipStream_t stream) {
  const float* mu    = (const float*)d_in[0];
  const float* sigma = (const float*)d_in[1];
  const float* label = (const float*)d_in[2];
  const float* maskp = (const float*)d_in[3];
  const float* prob  = (const float*)d_in[4];

  char* w = (char*)d_ws;
  size_t off = 0;
  auto alloc = [&](size_t bytes) -> void* {
    off = (off + 255) & ~(size_t)255;
    void* r = w + off;
    off += bytes;
    return r;
  };
  // small buffers (~11.6 MiB)
  float* denom     = (float*)alloc((size_t)P_ * 4);
  int*   segid     = (int*)alloc((size_t)P_ * 4);
  int*   hardf     = (int*)alloc((size_t)P_ * 4);
  int*   vlist     = (int*)alloc((size_t)S_ * P_ * 4);
  int*   hlist     = (int*)alloc((size_t)S_ * P_ * 4);
  int*   vcount    = (int*)alloc(S_ * 4);
  int*   hcount    = (int*)alloc(S_ * 4);
  float* proto_acc = (float*)alloc((size_t)C_ * 42 * 4);
  float* pmn       = (float*)alloc((size_t)S_ * C_ * 4);
  float* psig      = (float*)alloc((size_t)S_ * C_ * 4);
  float* logp      = (float*)alloc((size_t)S_ * 20 * 4);
  float* partials  = (float*)alloc((size_t)S_ * Q_ * 4);
  int*   countsV   = (int*)alloc((size_t)256 * S_ * 4);
  int*   countsH   = (int*)alloc((size_t)256 * S_ * 4);
  int*   offsV     = (int*)alloc((size_t)256 * S_ * 4);
  int*   offsH     = (int*)alloc((size_t)256 * S_ * 4);

  // fast-path buffers: packed feat 64 MiB + proto partials 44 MiB
  size_t feat_bytes = (size_t)P_ * 256 * 4;
  size_t part_bytes = (size_t)1024 * 10752 * 4;
  size_t need = ((off + 255) & ~(size_t)255) + feat_bytes + 256 + part_bytes;
  bool fast = (ws_size >= need);
  uint32_t* feat = fast ? (uint32_t*)alloc(feat_bytes) : nullptr;
  float*    part = fast ? (float*)alloc(part_bytes) : nullptr;

  k_prep<<<P_ / 256, 256, 0, stream>>>(mu, label, maskp, prob, denom, segid, hardf);
  k_count<<<256, 256, 0, stream>>>(segid, hardf, countsV, countsH);
  k_scan<<<1, 64, 0, stream>>>(countsV, countsH, offsV, offsH, vcount, hcount);
  k_scatter<<<256, 256, 0, stream>>>(segid, hardf, offsV, offsH, vlist, hlist);
  if (fast) {
    k_transpose<<<dim3(P_ / 64, C_ / 64), 256, 0, stream>>>(mu, sigma, denom, segid,
                                                            feat, part);
    k_proto_reduce<<<42, 256, 0, stream>>>(part, proto_acc);
  } else {
    k_proto_acc<<<C_, 256, 0, stream>>>(mu, sigma, segid, proto_acc);
  }
  k_proto_fin<<<S_, 256, 0, stream>>>(proto_acc, pmn, psig);
  k_logp<<<S_, 256, 0, stream>>>(pmn, psig, logp);
  if (fast) {
    k_main_fast<<<dim3(Q_, S_), 256, 0, stream>>>(feat, pmn, psig, logp,
                                                  vlist, hlist, vcount, hcount, partials);
  } else {
    k_main_slow<<<dim3(Q_, S_), 256, 0, stream>>>(mu, sigma, denom, pmn, psig, logp,
                                                  vlist, hlist, vcount, hcount, partials);
  }
  k_final<<<1, 256, 0, stream>>>(partials, vcount, hcount, (uint32_t*)d_out);
}

// Round 5
// 513.127 us; speedup vs baseline: 26.0922x; 1.2835x over previous
//
#include <hip/hip_runtime.h>
#include <stdint.h>

#define B_ 16
#define C_ 256
#define HW_ 4096
#define P_ 65536
#define S_ 21
#define Q_ 256
#define N_ 256
#define THR_ 0.97f
#define TINY_ 1.17549435e-38f

// ---------------- threefry-2x32, 20 rounds (matches JAX/Random123) ----------
__device__ __forceinline__ void tf2x32(uint32_t k0, uint32_t k1,
                                       uint32_t& x0, uint32_t& x1) {
  uint32_t k2 = k0 ^ k1 ^ 0x1BD11BDAu;
  uint32_t v0 = x0 + k0, v1 = x1 + k1;
#define TFR(r) { v0 += v1; v1 = (v1 << (r)) | (v1 >> (32 - (r))); v1 ^= v0; }
  TFR(13) TFR(15) TFR(26) TFR(6)  v0 += k1; v1 += k2 + 1u;
  TFR(17) TFR(29) TFR(16) TFR(24) v0 += k2; v1 += k0 + 2u;
  TFR(13) TFR(15) TFR(26) TFR(6)  v0 += k0; v1 += k1 + 3u;
  TFR(17) TFR(29) TFR(16) TFR(24) v0 += k1; v1 += k2 + 4u;
  TFR(13) TFR(15) TFR(26) TFR(6)  v0 += k2; v1 += k0 + 5u;
#undef TFR
  x0 = v0; x1 = v1;
}

__device__ __forceinline__ uint32_t tf_xor(uint32_t k0, uint32_t k1,
                                           uint32_t hi, uint32_t lo) {
  uint32_t a = hi, b = lo;
  tf2x32(k0, k1, a, b);
  return a ^ b;
}

// JAX uniform [0,1): ((bits>>9)|0x3f800000).view(f32) - 1
__device__ __forceinline__ float u01(uint32_t bits) {
  return __uint_as_float((bits >> 9) | 0x3f800000u) - 1.0f;
}

// f32 -> bf16 bits, round-nearest-even
__device__ __forceinline__ uint32_t f2bf(float x) {
  uint32_t u = __float_as_uint(x);
  return (u + 0x7FFFu + ((u >> 16) & 1u)) >> 16;
}
__device__ __forceinline__ float bf_lo(uint32_t v) {  // low 16 bits as bf16
  return __uint_as_float(v << 16);
}
__device__ __forceinline__ float bf_hi(uint32_t v) {  // high 16 bits as bf16
  return __uint_as_float(v & 0xFFFF0000u);
}

// ---------------- kernel 1: segment id, hard flag, mu row norms -------------
__global__ __launch_bounds__(256) void k_prep(
    const float* __restrict__ mu, const float* __restrict__ label,
    const float* __restrict__ maskp, const float* __restrict__ prob,
    float* __restrict__ denom, int* __restrict__ segid, int* __restrict__ hardf) {
  int p = blockIdx.x * 256 + threadIdx.x;
  int b = p >> 12, hw = p & 4095;
  float mv = maskp[p];
  int seg = -1, hf = 0;
  if (mv > 0.0f) {
    for (int s = 0; s < S_; ++s) {
      float lv = label[(size_t)((b * S_ + s) << 12) + hw];
      if (lv > 0.0f) {
        seg = s;
        hf = (prob[(size_t)((b * S_ + s) << 12) + hw] < THR_) ? 1 : 0;
      }
    }
  }
  segid[p] = seg; hardf[p] = hf;
  float ss = 0.0f;
  const float* mb = mu + ((size_t)b << 20) + hw;
  for (int c = 0; c < C_; ++c) {
    float v = mb[(size_t)c << 12];
    ss += v * v;
  }
  denom[p] = fmaxf(sqrtf(ss), 1e-12f);
}

// ---------------- counting sort phase 1: per-block per-segment counts -------
__global__ __launch_bounds__(256) void k_count(
    const int* __restrict__ segid, const int* __restrict__ hardf,
    int* __restrict__ countsV, int* __restrict__ countsH) {
  __shared__ int cV[S_], cH[S_];
  int tid = threadIdx.x;
  if (tid < S_) { cV[tid] = 0; cH[tid] = 0; }
  __syncthreads();
  int p = blockIdx.x * 256 + tid;
  int s = segid[p];
  if (s >= 0) {
    atomicAdd(&cV[s], 1);
    if (hardf[p]) atomicAdd(&cH[s], 1);
  }
  __syncthreads();
  if (tid < S_) {
    countsV[blockIdx.x * S_ + tid] = cV[tid];
    countsH[blockIdx.x * S_ + tid] = cH[tid];
  }
}

// ---------------- counting sort phase 2: exclusive scan over 256 blocks -----
__global__ __launch_bounds__(64) void k_scan(
    const int* __restrict__ countsV, const int* __restrict__ countsH,
    int* __restrict__ offsV, int* __restrict__ offsH,
    int* __restrict__ vcount, int* __restrict__ hcount) {
  int t = threadIdx.x;
  if (t >= 2 * S_) return;
  int s = (t < S_) ? t : (t - S_);
  bool isH = (t >= S_);
  const int* cnt = isH ? countsH : countsV;
  int* offs = isH ? offsH : offsV;
  int acc = 0;
  for (int bo = 0; bo < 256; ++bo) {
    offs[bo * S_ + s] = acc;
    acc += cnt[bo * S_ + s];
  }
  if (isH) hcount[s] = acc; else vcount[s] = acc;
}

// ---------------- counting sort phase 3: stable scatter ---------------------
__global__ __launch_bounds__(256) void k_scatter(
    const int* __restrict__ segid, const int* __restrict__ hardf,
    const int* __restrict__ offsV, const int* __restrict__ offsH,
    int* __restrict__ vlist, int* __restrict__ hlist) {
  __shared__ int wcV[4][S_], wcH[4][S_];
  __shared__ int wbV[4][S_], wbH[4][S_];
  int tid = threadIdx.x, lane = tid & 63, w = tid >> 6;
  int p = blockIdx.x * 256 + tid;
  int seg = segid[p];
  bool hard = (seg >= 0) && (hardf[p] != 0);
  unsigned long long lt = ((unsigned long long)1 << lane) - 1ull;
  int rankV = 0, rankH = 0;
  for (int s = 0; s < S_; ++s) {
    unsigned long long mV = __ballot(seg == s);
    unsigned long long mH = __ballot(hard && (seg == s));
    if (lane == 0) { wcV[w][s] = __popcll(mV); wcH[w][s] = __popcll(mH); }
    if (seg == s) { rankV = __popcll(mV & lt); rankH = __popcll(mH & lt); }
  }
  __syncthreads();
  if (tid < S_) {
    int aV = 0, aH = 0;
    for (int ww = 0; ww < 4; ++ww) {
      int t1 = wcV[ww][tid]; wbV[ww][tid] = aV; aV += t1;
      int t2 = wcH[ww][tid]; wbH[ww][tid] = aH; aH += t2;
    }
  }
  __syncthreads();
  if (seg >= 0) {
    vlist[seg * P_ + offsV[blockIdx.x * S_ + seg] + wbV[w][seg] + rankV] = p;
    if (hard)
      hlist[seg * P_ + offsH[blockIdx.x * S_ + seg] + wbH[w][seg] + rankH] = p;
  }
}

// ------- kernel: transpose -> packed bf16 feat + fused proto partials -------
__global__ __launch_bounds__(256) void k_transpose(
    const float* __restrict__ mu, const float* __restrict__ sigma,
    const float* __restrict__ denom, const int* __restrict__ segid,
    uint32_t* __restrict__ feat, float* __restrict__ part) {
  __shared__ float tmu[64][65];
  __shared__ float tsg[64][65];
  __shared__ float rdn[64];
  __shared__ int sseg[64];
  __shared__ float accA[S_][64];
  __shared__ float accB[S_][64];
  int tx = threadIdx.x & 63, ty = threadIdx.x >> 6;
  int p0 = blockIdx.x * 64;          // 64 | 4096 -> single batch b
  int c0 = blockIdx.y * 64;
  int b = p0 >> 12, hw0 = p0 & 4095;
  if (threadIdx.x < 64) {
    rdn[tx] = 1.0f / denom[p0 + tx];
    sseg[tx] = segid[p0 + tx];
  }
  for (int k = threadIdx.x; k < S_ * 64; k += 256) {
    ((float*)accA)[k] = 0.0f;
    ((float*)accB)[k] = 0.0f;
  }
  const size_t basein = ((size_t)b << 20) + (size_t)(hw0 + tx);
  for (int rr = 0; rr < 64; rr += 4) {
    int c = c0 + rr + ty;
    tmu[rr + ty][tx] = mu[basein + ((size_t)c << 12)];
    tsg[rr + ty][tx] = sigma[basein + ((size_t)c << 12)];
  }
  __syncthreads();
  // packed feat write (coalesced along c)
  for (int rr = 0; rr < 64; rr += 4) {
    int poff = rr + ty;
    size_t o = (size_t)(p0 + poff) * 256 + (size_t)(c0 + tx);
    float m = tmu[tx][poff] * rdn[poff];
    float sgv = tsg[tx][poff];
    feat[o] = f2bf(m) | (f2bf(sgv) << 16);
  }
  // deterministic proto partials: one thread per channel, pixels ascending
  if (threadIdx.x < 64) {
    int cc = threadIdx.x;
    for (int pp = 0; pp < 64; ++pp) {
      int s = sseg[pp];
      if (s >= 0) {
        float sg = tsg[cc][pp];
        float inv = 1.0f / sg;
        accA[s][cc] += inv;
        accB[s][cc] += tmu[cc][pp] * inv;
      }
    }
  }
  __syncthreads();
  float* dst = part + (size_t)blockIdx.x * 10752 + (size_t)blockIdx.y * 2688;
  for (int k = threadIdx.x; k < S_ * 64; k += 256) {
    int s = k >> 6, cc = k & 63;
    dst[k * 2] = accA[s][cc];
    dst[k * 2 + 1] = accB[s][cc];
  }
}

// ---------------- reduce proto partials over 1024 pixel-blocks --------------
__global__ __launch_bounds__(256) void k_proto_reduce(
    const float* __restrict__ part, float* __restrict__ proto_acc) {
  int j = blockIdx.x * 256 + threadIdx.x;          // 42 blocks x 256 = 10752
  int t = j & 1;
  int cc = (j >> 1) & 63;
  int rest = j >> 7;                                // cb*21 + s
  int s = rest % S_;
  int cb = rest / S_;
  float sum = 0.0f;
  for (int pb = 0; pb < 1024; ++pb) sum += part[(size_t)pb * 10752 + j];
  proto_acc[(cb * 64 + cc) * 42 + s * 2 + t] = sum;
}

// ------- fallback proto accumulation (small-workspace path) -----------------
__global__ __launch_bounds__(256) void k_proto_acc(
    const float* __restrict__ mu, const float* __restrict__ sigma,
    const int* __restrict__ segid, float* __restrict__ proto_acc) {
  __shared__ float acc[256][42];
  int c = blockIdx.x, tid = threadIdx.x;
  for (int k = 0; k < 42; ++k) acc[tid][k] = 0.0f;
  for (int it = 0; it < 256; ++it) {
    int p = it * 256 + tid;
    int s = segid[p];
    if (s >= 0) {
      int b = p >> 12, hw = p & 4095;
      size_t o = ((size_t)b << 20) + ((size_t)c << 12) + (size_t)hw;
      float inv = 1.0f / sigma[o];
      acc[tid][s * 2] += inv;
      acc[tid][s * 2 + 1] += mu[o] * inv;
    }
  }
  __syncthreads();
  if (tid < 42) {
    float t = 0.0f;
    for (int r = 0; r < 256; ++r) t += acc[r][tid];
    proto_acc[c * 42 + tid] = t;
  }
}

// -------- finalize protos; also write packed bf16 proto rows to feat --------
__global__ __launch_bounds__(256) void k_proto_fin(
    const float* __restrict__ proto_acc,
    float* __restrict__ pmn, float* __restrict__ psig,
    uint32_t* __restrict__ feat) {   // feat nullable (slow path)
  __shared__ float red[256];
  __shared__ float dsh;
  int s = blockIdx.x, c = threadIdx.x;
  float sx = proto_acc[c * 42 + s * 2];
  float sy = proto_acc[c * 42 + s * 2 + 1];
  float ps = 1.0f / sx;
  float pm = ps * sy;
  red[c] = pm * pm;
  __syncthreads();
  for (int st = 128; st > 0; st >>= 1) {
    if (c < st) red[c] += red[c + st];
    __syncthreads();
  }
  if (c == 0) dsh = fmaxf(sqrtf(red[0]), 1e-12f);
  __syncthreads();
  float pmnv = pm / dsh;
  pmn[s * 256 + c] = pmnv;
  psig[s * 256 + c] = ps;
  if (feat) feat[(size_t)(P_ + s) * 256 + c] = f2bf(pmnv) | (f2bf(ps) << 16);
}

// ---------------- proto similarity -> log_softmax ---------------------------
__global__ __launch_bounds__(256) void k_logp(
    const float* __restrict__ pmn, const float* __restrict__ psig,
    float* __restrict__ logp) {
  __shared__ float red[256];
  __shared__ float sim[20];
  int i = blockIdx.x, c = threadIdx.x;
  float pmi = pmn[i * 256 + c];
  float psi = psig[i * 256 + c];
  for (int t = 0; t < 20; ++t) {
    int o = (i + 1 + t) % S_;
    float d = pmi - pmn[o * 256 + c];
    float sdn = psi + psig[o * 256 + c];
    red[c] = d * d / sdn + __logf(sdn);
    __syncthreads();
    for (int st = 128; st > 0; st >>= 1) {
      if (c < st) red[c] += red[c + st];
      __syncthreads();
    }
    if (c == 0) sim[t] = -red[0] * (1.0f / 256.0f);  // (-0.5*mean)/0.5 == -mean
    __syncthreads();
  }
  if (c == 0) {
    float mx = -3.4e38f;
    for (int t = 0; t < 20; ++t) mx = fmaxf(mx, sim[t]);
    float se = 0.0f;
    for (int t = 0; t < 20; ++t) se += __expf(sim[t] - mx);
    float ls = __logf(se);
    for (int t = 0; t < 20; ++t) logp[i * 20 + t] = sim[t] - mx - ls;
  }
}

// ---------------- main per-(segment, query) loss ----------------------------
// FAST=1: packed bf16 rows feat[P+32][256] u32, 8-lanes-per-logit
// FAST=0: NCHW gather fallback (round-4 code, unchanged)
template <int FAST>
__device__ __forceinline__ void main_body(
    const uint32_t* __restrict__ featu,
    const float* __restrict__ mu, const float* __restrict__ sigma,
    const float* __restrict__ denom,
    const float* __restrict__ pmn, const float* __restrict__ psig,
    const float* __restrict__ logp,
    const int* __restrict__ vlist, const int* __restrict__ hlist,
    const int* __restrict__ vcount, const int* __restrict__ hcount,
    float* __restrict__ partials) {
  int q = blockIdx.x, i = blockIdx.y;
  int tid = threadIdx.x, lane = tid & 63, wid = tid >> 6;
  int hc = hcount[i];
  if (hc <= 0) { if (tid == 0) partials[i * Q_ + q] = 0.0f; return; }

  __shared__ __align__(16) float amu[256];
  __shared__ __align__(16) float asg[256];
  __shared__ int nidx[256];
  __shared__ float lgp[20];
  __shared__ float lgt[257];

  // key = fold_in(key(42), i); k1,k2,k3 = split (partitionable: full blocks)
  uint32_t kf0 = 0u, kf1 = (uint32_t)i;
  tf2x32(0u, 42u, kf0, kf1);
  uint32_t k1a = 0u, k1b = 0u; tf2x32(kf0, kf1, k1a, k1b);
  uint32_t k2a = 0u, k2b = 1u; tf2x32(kf0, kf1, k2a, k2b);
  uint32_t k3a = 0u, k3b = 2u; tf2x32(kf0, kf1, k3a, k3b);

  // anchor: jq = trunc(u * hcount), a_idx = hlist[i][jq]
  uint32_t ab = tf_xor(k1a, k1b, 0u, (uint32_t)q);
  float ua = fmaxf(0.0f, u01(ab));
  int jq = (int)(ua * (float)hc);
  jq = min(max(jq, 0), hc - 1);
  int a_idx = hlist[i * P_ + jq];
  if (FAST) {
    uint32_t v = featu[(size_t)a_idx * 256 + tid];
    amu[tid] = bf_lo(v);
    asg[tid] = bf_hi(v);
  } else {
    int b = a_idx >> 12, hw = a_idx & 4095;
    float rdnv = 1.0f / denom[a_idx];
    size_t base = ((size_t)b << 20) + (size_t)hw + ((size_t)tid << 12);
    amu[tid] = mu[base] * rdnv;
    asg[tid] = sigma[base];
  }
  if (tid < 20) lgp[tid] = logp[i * 20 + tid];
  __syncthreads();

  // negative sampling: thread tid == n. Gumbel-argmax over 20 classes.
  {
    int n = tid;
    uint32_t base = ((uint32_t)q * 256u + (uint32_t)n) * 20u;
    float best = -3.4e38f; int arg = 0;
    for (int t = 0; t < 20; ++t) {
      uint32_t bits = tf_xor(k2a, k2b, 0u, base + (uint32_t)t);
      float f = u01(bits);
      float u = fmaxf(TINY_, f + TINY_);           // uniform(minval=tiny)
      float g = -__logf(-__logf(u));
      float sc = g + lgp[t];
      if (sc > best) { best = sc; arg = t; }       // first-max wins
    }
    int nseg = (i + 1 + arg) % S_;
    int cnt = vcount[nseg];
    uint32_t b3 = tf_xor(k3a, k3b, 0u, (uint32_t)q * 256u + (uint32_t)n);
    float u3 = fmaxf(0.0f, u01(b3));
    int jp = (int)(u3 * (float)cnt);
    jp = min(max(jp, 0), max(cnt - 1, 0));
    nidx[n] = vlist[nseg * P_ + jp];
  }
  __syncthreads();

  if (FAST) {
    // 8 lanes per logit: sublane t = lane&7 owns channels (k*8+t)*4, k=0..7.
    int t = lane & 7, g = lane >> 3;
    // anchor channels into registers (one-time LDS read)
    float4 am[8], as[8];
#pragma unroll
    for (int k = 0; k < 8; ++k) {
      int cb = (k * 8 + t) << 2;
      am[k] = *(const float4*)(amu + cb);
      as[k] = *(const float4*)(asg + cb);
    }
    for (int jb = 0; jb < 288; jb += 32) {
      int j = jb + (wid << 3) + g;
      float acc = 0.0f;
      if (j < 257) {
        int rid = (j == 0) ? (P_ + i) : nidx[j - 1];
        const uint32_t* __restrict__ row = featu + (size_t)rid * 256;
        float pacc = 1.0f;
#pragma unroll
        for (int k = 0; k < 8; ++k) {
          uint4 pv = *(const uint4*)(row + ((k * 8 + t) << 2));
          float bm0 = bf_lo(pv.x), bs0 = bf_hi(pv.x);
          float bm1 = bf_lo(pv.y), bs1 = bf_hi(pv.y);
          float bm2 = bf_lo(pv.z), bs2 = bf_hi(pv.z);
          float bm3 = bf_lo(pv.w), bs3 = bf_hi(pv.w);
          float d0 = am[k].x - bm0, s0 = as[k].x + bs0;
          float d1 = am[k].y - bm1, s1 = as[k].y + bs1;
          float d2 = am[k].z - bm2, s2 = as[k].z + bs2;
          float d3 = am[k].w - bm3, s3 = as[k].w + bs3;
          acc = fmaf(d0 * d0, __builtin_amdgcn_rcpf(s0), acc);
          acc = fmaf(d1 * d1, __builtin_amdgcn_rcpf(s1), acc);
          acc = fmaf(d2 * d2, __builtin_amdgcn_rcpf(s2), acc);
          acc = fmaf(d3 * d3, __builtin_amdgcn_rcpf(s3), acc);
          pacc *= (s0 * s1) * (s2 * s3);   // in [4e-23, 9e10]: safe in f32
        }
        acc += __logf(pacc);
      }
      // reduce within the 8-lane group
      acc += __shfl_xor(acc, 1, 64);
      acc += __shfl_xor(acc, 2, 64);
      acc += __shfl_xor(acc, 4, 64);
      if (t == 0 && j < 257) lgt[j] = -acc * (1.0f / 256.0f);
    }
  } else {
    // round-4 wave-per-logit fallback
    int c0 = lane * 4;
    float4 am4 = *(const float4*)(amu + c0);
    float4 as4 = *(const float4*)(asg + c0);
    for (int j = wid; j < 257; j += 4) {
      float bm0, bm1, bm2, bm3, bs0, bs1, bs2, bs3;
      if (j == 0) {
        float4 bm4 = *(const float4*)(pmn + i * 256 + c0);
        float4 bs4 = *(const float4*)(psig + i * 256 + c0);
        bm0 = bm4.x; bm1 = bm4.y; bm2 = bm4.z; bm3 = bm4.w;
        bs0 = bs4.x; bs1 = bs4.y; bs2 = bs4.z; bs3 = bs4.w;
      } else {
        int pix = nidx[j - 1];
        int b = pix >> 12, hw = pix & 4095;
        float rdnv = 1.0f / denom[pix];
        size_t base = ((size_t)b << 20) + (size_t)hw + ((size_t)(c0) << 12);
        bm0 = mu[base] * rdnv;          bs0 = sigma[base];
        bm1 = mu[base + 4096] * rdnv;   bs1 = sigma[base + 4096];
        bm2 = mu[base + 8192] * rdnv;   bs2 = sigma[base + 8192];
        bm3 = mu[base + 12288] * rdnv;  bs3 = sigma[base + 12288];
      }
      float d0 = am4.x - bm0, s0 = as4.x + bs0;
      float d1 = am4.y - bm1, s1 = as4.y + bs1;
      float d2 = am4.z - bm2, s2 = as4.z + bs2;
      float d3 = am4.w - bm3, s3 = as4.w + bs3;
      float acc = d0 * d0 / s0 + __logf(s0);
      acc += d1 * d1 / s1 + __logf(s1);
      acc += d2 * d2 / s2 + __logf(s2);
      acc += d3 * d3 / s3 + __logf(s3);
      for (int off = 32; off > 0; off >>= 1) acc += __shfl_xor(acc, off, 64);
      if (lane == 0) lgt[j] = -acc * (1.0f / 256.0f);
    }
  }
  __syncthreads();

  if (wid == 0) {
    float mx = -3.4e38f;
    for (int j = lane; j < 257; j += 64) mx = fmaxf(mx, lgt[j]);
    for (int off = 32; off > 0; off >>= 1) mx = fmaxf(mx, __shfl_xor(mx, off, 64));
    float se = 0.0f;
    for (int j = lane; j < 257; j += 64) se += __expf(lgt[j] - mx);
    for (int off = 32; off > 0; off >>= 1) se += __shfl_xor(se, off, 64);
    if (lane == 0) partials[i * Q_ + q] = __logf(se) + mx - lgt[0];
  }
}

__global__ __launch_bounds__(256) void k_main_fast(
    const uint32_t* __restrict__ featu,
    const float* __restrict__ pmn, const float* __restrict__ psig,
    const float* __restrict__ logp,
    const int* __restrict__ vlist, const int* __restrict__ hlist,
    const int* __restrict__ vcount, const int* __restrict__ hcount,
    float* __restrict__ partials) {
  main_body<1>(featu, nullptr, nullptr, nullptr, pmn, psig, logp,
               vlist, hlist, vcount, hcount, partials);
}

__global__ __launch_bounds__(256) void k_main_slow(
    const float* __restrict__ mu, const float* __restrict__ sigma,
    const float* __restrict__ denom,
    const float* __restrict__ pmn, const float* __restrict__ psig,
    const float* __restrict__ logp,
    const int* __restrict__ vlist, const int* __restrict__ hlist,
    const int* __restrict__ vcount, const int* __restrict__ hcount,
    float* __restrict__ partials) {
  main_body<0>(nullptr, mu, sigma, denom, pmn, psig, logp,
               vlist, hlist, vcount, hcount, partials);
}

// ---------------- final reduction, dtype-hedged output ----------------------
__global__ __launch_bounds__(256) void k_final(
    const float* __restrict__ partials, const int* __restrict__ vcount,
    const int* __restrict__ hcount, uint32_t* __restrict__ out) {
  __shared__ float ces[S_];
  int tid = threadIdx.x;
  if (tid < S_) {
    float s = 0.0f;
    for (int qq = 0; qq < Q_; ++qq) s += partials[tid * Q_ + qq];
    ces[tid] = (hcount[tid] > 0) ? (s * (1.0f / Q_)) : 0.0f;
  }
  __syncthreads();
  if (tid == 0) {
    float tot = 0.0f, vn = 0.0f;
    for (int s2 = 0; s2 < S_; ++s2) {
      tot += ces[s2];
      if (vcount[s2] > 0) vn += 1.0f;
    }
    float val = tot / vn;
    uint32_t u = __float_as_uint(val);
    uint32_t bf = (u + 0x7FFFu + ((u >> 16) & 1u)) >> 16;  // f32 -> bf16 RNE
    out[0] = (bf << 16) | bf;
  }
}

extern "C" void kernel_launch(void* const* d_in, const int* in_sizes, int n_in,
                              void* d_out, int out_size, void* d_ws, size_t ws_size,
                              hipStream_t stream) {
  const float* mu    = (const float*)d_in[0];
  const float* sigma = (const float*)d_in[1];
  const float* label = (const float*)d_in[2];
  const float* maskp = (const float*)d_in[3];
  const float* prob  = (const float*)d_in[4];

  char* w = (char*)d_ws;
  size_t off = 0;
  auto alloc = [&](size_t bytes) -> void* {
    off = (off + 255) & ~(size_t)255;
    void* r = w + off;
    off += bytes;
    return r;
  };
  // small buffers (~11.6 MiB)
  float* denom     = (float*)alloc((size_t)P_ * 4);
  int*   segid     = (int*)alloc((size_t)P_ * 4);
  int*   hardf     = (int*)alloc((size_t)P_ * 4);
  int*   vlist     = (int*)alloc((size_t)S_ * P_ * 4);
  int*   hlist     = (int*)alloc((size_t)S_ * P_ * 4);
  int*   vcount    = (int*)alloc(S_ * 4);
  int*   hcount    = (int*)alloc(S_ * 4);
  float* proto_acc = (float*)alloc((size_t)C_ * 42 * 4);
  float* pmn       = (float*)alloc((size_t)S_ * C_ * 4);
  float* psig      = (float*)alloc((size_t)S_ * C_ * 4);
  float* logp      = (float*)alloc((size_t)S_ * 20 * 4);
  float* partials  = (float*)alloc((size_t)S_ * Q_ * 4);
  int*   countsV   = (int*)alloc((size_t)256 * S_ * 4);
  int*   countsH   = (int*)alloc((size_t)256 * S_ * 4);
  int*   offsV     = (int*)alloc((size_t)256 * S_ * 4);
  int*   offsH     = (int*)alloc((size_t)256 * S_ * 4);

  // fast-path buffers: packed feat (P_+32 rows) 64 MiB + proto partials 44 MiB
  size_t feat_bytes = (size_t)(P_ + 32) * 256 * 4;
  size_t part_bytes = (size_t)1024 * 10752 * 4;
  size_t need = ((off + 255) & ~(size_t)255) + feat_bytes + 256 + part_bytes;
  bool fast = (ws_size >= need);
  uint32_t* feat = fast ? (uint32_t*)alloc(feat_bytes) : nullptr;
  float*    part = fast ? (float*)alloc(part_bytes) : nullptr;

  k_prep<<<P_ / 256, 256, 0, stream>>>(mu, label, maskp, prob, denom, segid, hardf);
  k_count<<<256, 256, 0, stream>>>(segid, hardf, countsV, countsH);
  k_scan<<<1, 64, 0, stream>>>(countsV, countsH, offsV, offsH, vcount, hcount);
  k_scatter<<<256, 256, 0, stream>>>(segid, hardf, offsV, offsH, vlist, hlist);
  if (fast) {
    k_transpose<<<dim3(P_ / 64, C_ / 64), 256, 0, stream>>>(mu, sigma, denom, segid,
                                                            feat, part);
    k_proto_reduce<<<42, 256, 0, stream>>>(part, proto_acc);
  } else {
    k_proto_acc<<<C_, 256, 0, stream>>>(mu, sigma, segid, proto_acc);
  }
  k_proto_fin<<<S_, 256, 0, stream>>>(proto_acc, pmn, psig, feat);
  k_logp<<<S_, 256, 0, stream>>>(pmn, psig, logp);
  if (fast) {
    k_main_fast<<<dim3(Q_, S_), 256, 0, stream>>>(feat, pmn, psig, logp,
                                                  vlist, hlist, vcount, hcount, partials);
  } else {
    k_main_slow<<<dim3(Q_, S_), 256, 0, stream>>>(mu, sigma, denom, pmn, psig, logp,
                                                  vlist, hlist, vcount, hcount, partials);
  }
  k_final<<<1, 256, 0, stream>>>(partials, vcount, hcount, (uint32_t*)d_out);
}

// Round 6
// 463.455 us; speedup vs baseline: 28.8888x; 1.1072x over previous
//
#include <hip/hip_runtime.h>
#include <stdint.h>

#define B_ 16
#define C_ 256
#define HW_ 4096
#define P_ 65536
#define S_ 21
#define Q_ 256
#define N_ 256
#define THR_ 0.97f
#define TINY_ 1.17549435e-38f

// ---------------- threefry-2x32, 20 rounds (matches JAX/Random123) ----------
__device__ __forceinline__ void tf2x32(uint32_t k0, uint32_t k1,
                                       uint32_t& x0, uint32_t& x1) {
  uint32_t k2 = k0 ^ k1 ^ 0x1BD11BDAu;
  uint32_t v0 = x0 + k0, v1 = x1 + k1;
#define TFR(r) { v0 += v1; v1 = (v1 << (r)) | (v1 >> (32 - (r))); v1 ^= v0; }
  TFR(13) TFR(15) TFR(26) TFR(6)  v0 += k1; v1 += k2 + 1u;
  TFR(17) TFR(29) TFR(16) TFR(24) v0 += k2; v1 += k0 + 2u;
  TFR(13) TFR(15) TFR(26) TFR(6)  v0 += k0; v1 += k1 + 3u;
  TFR(17) TFR(29) TFR(16) TFR(24) v0 += k1; v1 += k2 + 4u;
  TFR(13) TFR(15) TFR(26) TFR(6)  v0 += k2; v1 += k0 + 5u;
#undef TFR
  x0 = v0; x1 = v1;
}

__device__ __forceinline__ uint32_t tf_xor(uint32_t k0, uint32_t k1,
                                           uint32_t hi, uint32_t lo) {
  uint32_t a = hi, b = lo;
  tf2x32(k0, k1, a, b);
  return a ^ b;
}

// JAX uniform [0,1): ((bits>>9)|0x3f800000).view(f32) - 1
__device__ __forceinline__ float u01(uint32_t bits) {
  return __uint_as_float((bits >> 9) | 0x3f800000u) - 1.0f;
}

// f32 -> bf16 bits, round-nearest-even
__device__ __forceinline__ uint32_t f2bf(float x) {
  uint32_t u = __float_as_uint(x);
  return (u + 0x7FFFu + ((u >> 16) & 1u)) >> 16;
}
__device__ __forceinline__ float bf_lo(uint32_t v) {
  return __uint_as_float(v << 16);
}
__device__ __forceinline__ float bf_hi(uint32_t v) {
  return __uint_as_float(v & 0xFFFF0000u);
}

// ---------------- fast: segid/hardf only (no mu read) -----------------------
__global__ __launch_bounds__(256) void k_prep_light(
    const float* __restrict__ label, const float* __restrict__ maskp,
    const float* __restrict__ prob,
    int* __restrict__ segid, int* __restrict__ hardf) {
  int p = blockIdx.x * 256 + threadIdx.x;
  int b = p >> 12, hw = p & 4095;
  float mv = maskp[p];
  int seg = -1, hf = 0;
  if (mv > 0.0f) {
    for (int s = 0; s < S_; ++s) {
      float lv = label[(size_t)((b * S_ + s) << 12) + hw];
      if (lv > 0.0f) {
        seg = s;
        hf = (prob[(size_t)((b * S_ + s) << 12) + hw] < THR_) ? 1 : 0;
      }
    }
  }
  segid[p] = seg; hardf[p] = hf;
}

// ---------------- slow-path prep (also computes denom) ----------------------
__global__ __launch_bounds__(256) void k_prep(
    const float* __restrict__ mu, const float* __restrict__ label,
    const float* __restrict__ maskp, const float* __restrict__ prob,
    float* __restrict__ denom, int* __restrict__ segid, int* __restrict__ hardf) {
  int p = blockIdx.x * 256 + threadIdx.x;
  int b = p >> 12, hw = p & 4095;
  float mv = maskp[p];
  int seg = -1, hf = 0;
  if (mv > 0.0f) {
    for (int s = 0; s < S_; ++s) {
      float lv = label[(size_t)((b * S_ + s) << 12) + hw];
      if (lv > 0.0f) {
        seg = s;
        hf = (prob[(size_t)((b * S_ + s) << 12) + hw] < THR_) ? 1 : 0;
      }
    }
  }
  segid[p] = seg; hardf[p] = hf;
  float ss = 0.0f;
  const float* mb = mu + ((size_t)b << 20) + hw;
  for (int c = 0; c < C_; ++c) {
    float v = mb[(size_t)c << 12];
    ss += v * v;
  }
  denom[p] = fmaxf(sqrtf(ss), 1e-12f);
}

// ---------------- counting sort phase 1 -------------------------------------
__global__ __launch_bounds__(256) void k_count(
    const int* __restrict__ segid, const int* __restrict__ hardf,
    int* __restrict__ countsV, int* __restrict__ countsH) {
  __shared__ int cV[S_], cH[S_];
  int tid = threadIdx.x;
  if (tid < S_) { cV[tid] = 0; cH[tid] = 0; }
  __syncthreads();
  int p = blockIdx.x * 256 + tid;
  int s = segid[p];
  if (s >= 0) {
    atomicAdd(&cV[s], 1);
    if (hardf[p]) atomicAdd(&cH[s], 1);
  }
  __syncthreads();
  if (tid < S_) {
    countsV[blockIdx.x * S_ + tid] = cV[tid];
    countsH[blockIdx.x * S_ + tid] = cH[tid];
  }
}

// ---------------- counting sort phase 2 -------------------------------------
__global__ __launch_bounds__(64) void k_scan(
    const int* __restrict__ countsV, const int* __restrict__ countsH,
    int* __restrict__ offsV, int* __restrict__ offsH,
    int* __restrict__ vcount, int* __restrict__ hcount) {
  int t = threadIdx.x;
  if (t >= 2 * S_) return;
  int s = (t < S_) ? t : (t - S_);
  bool isH = (t >= S_);
  const int* cnt = isH ? countsH : countsV;
  int* offs = isH ? offsH : offsV;
  int acc = 0;
  for (int bo = 0; bo < 256; ++bo) {
    offs[bo * S_ + s] = acc;
    acc += cnt[bo * S_ + s];
  }
  if (isH) hcount[s] = acc; else vcount[s] = acc;
}

// ---------------- counting sort phase 3: stable scatter ---------------------
__global__ __launch_bounds__(256) void k_scatter(
    const int* __restrict__ segid, const int* __restrict__ hardf,
    const int* __restrict__ offsV, const int* __restrict__ offsH,
    int* __restrict__ vlist, int* __restrict__ hlist) {
  __shared__ int wcV[4][S_], wcH[4][S_];
  __shared__ int wbV[4][S_], wbH[4][S_];
  int tid = threadIdx.x, lane = tid & 63, w = tid >> 6;
  int p = blockIdx.x * 256 + tid;
  int seg = segid[p];
  bool hard = (seg >= 0) && (hardf[p] != 0);
  unsigned long long lt = ((unsigned long long)1 << lane) - 1ull;
  int rankV = 0, rankH = 0;
  for (int s = 0; s < S_; ++s) {
    unsigned long long mV = __ballot(seg == s);
    unsigned long long mH = __ballot(hard && (seg == s));
    if (lane == 0) { wcV[w][s] = __popcll(mV); wcH[w][s] = __popcll(mH); }
    if (seg == s) { rankV = __popcll(mV & lt); rankH = __popcll(mH & lt); }
  }
  __syncthreads();
  if (tid < S_) {
    int aV = 0, aH = 0;
    for (int ww = 0; ww < 4; ++ww) {
      int t1 = wcV[ww][tid]; wbV[ww][tid] = aV; aV += t1;
      int t2 = wcH[ww][tid]; wbH[ww][tid] = aH; aH += t2;
    }
  }
  __syncthreads();
  if (seg >= 0) {
    vlist[seg * P_ + offsV[blockIdx.x * S_ + seg] + wbV[w][seg] + rankV] = p;
    if (hard)
      hlist[seg * P_ + offsH[blockIdx.x * S_ + seg] + wbH[w][seg] + rankH] = p;
  }
}

// ------- transpose -> packed raw-bf16 feat + proto partials + sumsq ---------
__global__ __launch_bounds__(256) void k_transpose(
    const float* __restrict__ mu, const float* __restrict__ sigma,
    const int* __restrict__ segid,
    uint32_t* __restrict__ feat, float* __restrict__ part,
    float* __restrict__ ssqp) {
  __shared__ float tmu[64][65];
  __shared__ float tsg[64][65];
  __shared__ int sseg[64];
  __shared__ float accA[S_][64];
  __shared__ float accB[S_][64];
  __shared__ float ssq[4][64];
  int tx = threadIdx.x & 63, ty = threadIdx.x >> 6;
  int p0 = blockIdx.x * 64;
  int c0 = blockIdx.y * 64;
  int b = p0 >> 12, hw0 = p0 & 4095;
  if (threadIdx.x < 64) sseg[tx] = segid[p0 + tx];
  for (int k = threadIdx.x; k < S_ * 64; k += 256) {
    ((float*)accA)[k] = 0.0f;
    ((float*)accB)[k] = 0.0f;
  }
  const size_t basein = ((size_t)b << 20) + (size_t)(hw0 + tx);
  for (int rr = 0; rr < 64; rr += 4) {
    int c = c0 + rr + ty;
    tmu[rr + ty][tx] = mu[basein + ((size_t)c << 12)];
    tsg[rr + ty][tx] = sigma[basein + ((size_t)c << 12)];
  }
  __syncthreads();
  // packed raw feat write (coalesced along c)
  for (int rr = 0; rr < 64; rr += 4) {
    int poff = rr + ty;
    size_t o = (size_t)(p0 + poff) * 256 + (size_t)(c0 + tx);
    feat[o] = f2bf(tmu[tx][poff]) | (f2bf(tsg[tx][poff]) << 16);
  }
  // per-pixel partial sum of squares over this 64-channel tile
  {
    float s = 0.0f;
    for (int cc = ty * 16; cc < ty * 16 + 16; ++cc) {
      float v = tmu[cc][tx];
      s += v * v;
    }
    ssq[ty][tx] = s;
  }
  // deterministic proto partials: one thread per channel, pixels ascending
  if (threadIdx.x < 64) {
    int cc = threadIdx.x;
    for (int pp = 0; pp < 64; ++pp) {
      int s = sseg[pp];
      if (s >= 0) {
        float inv = 1.0f / tsg[cc][pp];
        accA[s][cc] += inv;
        accB[s][cc] += tmu[cc][pp] * inv;
      }
    }
  }
  __syncthreads();
  if (threadIdx.x < 64)
    ssqp[(size_t)blockIdx.y * P_ + p0 + tx] =
        ssq[0][tx] + ssq[1][tx] + ssq[2][tx] + ssq[3][tx];
  float* dst = part + (size_t)blockIdx.x * 10752 + (size_t)blockIdx.y * 2688;
  for (int k = threadIdx.x; k < S_ * 64; k += 256) {
    int s = k >> 6, cc = k & 63;
    dst[k * 2] = accA[s][cc];
    dst[k * 2 + 1] = accB[s][cc];
  }
}

// ---------------- finalize per-pixel reciprocal norms -----------------------
__global__ __launch_bounds__(256) void k_norm_fin(
    const float* __restrict__ ssqp, float* __restrict__ rdn) {
  int p = blockIdx.x * 256 + threadIdx.x;
  float s = ssqp[p] + ssqp[P_ + p] + ssqp[2 * P_ + p] + ssqp[3 * P_ + p];
  rdn[p] = 1.0f / fmaxf(sqrtf(s), 1e-12f);
}

// ---------------- proto partial reduce, stage A (1024 -> 32) ----------------
__global__ __launch_bounds__(256) void k_reduceA(
    const float* __restrict__ part, float* __restrict__ partA) {
  int j = blockIdx.x * 256 + threadIdx.x;   // 42 x-blocks
  int y = blockIdx.y;                        // 32 y-blocks
  float sum = 0.0f;
  for (int pb = y * 32; pb < y * 32 + 32; ++pb)
    sum += part[(size_t)pb * 10752 + j];
  partA[(size_t)y * 10752 + j] = sum;
}

// ---------------- proto partial reduce, stage B (32 -> 1, unscramble) -------
__global__ __launch_bounds__(256) void k_reduceB(
    const float* __restrict__ partA, float* __restrict__ proto_acc) {
  int j = blockIdx.x * 256 + threadIdx.x;
  int t = j & 1;
  int cc = (j >> 1) & 63;
  int rest = j >> 7;                         // cb*21 + s
  int s = rest % S_;
  int cb = rest / S_;
  float sum = 0.0f;
  for (int y = 0; y < 32; ++y) sum += partA[(size_t)y * 10752 + j];
  proto_acc[(cb * 64 + cc) * 42 + s * 2 + t] = sum;
}

// ------- fallback proto accumulation (small-workspace path) -----------------
__global__ __launch_bounds__(256) void k_proto_acc(
    const float* __restrict__ mu, const float* __restrict__ sigma,
    const int* __restrict__ segid, float* __restrict__ proto_acc) {
  __shared__ float acc[256][42];
  int c = blockIdx.x, tid = threadIdx.x;
  for (int k = 0; k < 42; ++k) acc[tid][k] = 0.0f;
  for (int it = 0; it < 256; ++it) {
    int p = it * 256 + tid;
    int s = segid[p];
    if (s >= 0) {
      int b = p >> 12, hw = p & 4095;
      size_t o = ((size_t)b << 20) + ((size_t)c << 12) + (size_t)hw;
      float inv = 1.0f / sigma[o];
      acc[tid][s * 2] += inv;
      acc[tid][s * 2 + 1] += mu[o] * inv;
    }
  }
  __syncthreads();
  if (tid < 42) {
    float t = 0.0f;
    for (int r = 0; r < 256; ++r) t += acc[r][tid];
    proto_acc[c * 42 + tid] = t;
  }
}

// ---------------- finalize protos (normalized mu, sigma) --------------------
__global__ __launch_bounds__(256) void k_proto_fin(
    const float* __restrict__ proto_acc,
    float* __restrict__ pmn, float* __restrict__ psig) {
  __shared__ float red[256];
  __shared__ float dsh;
  int s = blockIdx.x, c = threadIdx.x;
  float sx = proto_acc[c * 42 + s * 2];
  float sy = proto_acc[c * 42 + s * 2 + 1];
  float ps = 1.0f / sx;
  float pm = ps * sy;
  red[c] = pm * pm;
  __syncthreads();
  for (int st = 128; st > 0; st >>= 1) {
    if (c < st) red[c] += red[c + st];
    __syncthreads();
  }
  if (c == 0) dsh = fmaxf(sqrtf(red[0]), 1e-12f);
  __syncthreads();
  pmn[s * 256 + c] = pm / dsh;
  psig[s * 256 + c] = ps;
}

// ---------------- proto similarity -> log_softmax ---------------------------
__global__ __launch_bounds__(256) void k_logp(
    const float* __restrict__ pmn, const float* __restrict__ psig,
    float* __restrict__ logp) {
  __shared__ float red[256];
  __shared__ float sim[20];
  int i = blockIdx.x, c = threadIdx.x;
  float pmi = pmn[i * 256 + c];
  float psi = psig[i * 256 + c];
  for (int t = 0; t < 20; ++t) {
    int o = (i + 1 + t) % S_;
    float d = pmi - pmn[o * 256 + c];
    float sdn = psi + psig[o * 256 + c];
    red[c] = d * d / sdn + __logf(sdn);
    __syncthreads();
    for (int st = 128; st > 0; st >>= 1) {
      if (c < st) red[c] += red[c + st];
      __syncthreads();
    }
    if (c == 0) sim[t] = -red[0] * (1.0f / 256.0f);
    __syncthreads();
  }
  if (c == 0) {
    float mx = -3.4e38f;
    for (int t = 0; t < 20; ++t) mx = fmaxf(mx, sim[t]);
    float se = 0.0f;
    for (int t = 0; t < 20; ++t) se += __expf(sim[t] - mx);
    float ls = __logf(se);
    for (int t = 0; t < 20; ++t) logp[i * 20 + t] = sim[t] - mx - ls;
  }
}

// ---------------- main: fast path (raw bf16 feat, rdn fma-normalize) --------
__global__ __launch_bounds__(256) void k_main_fast(
    const uint32_t* __restrict__ feat, const float* __restrict__ rdn,
    const float* __restrict__ pmn, const float* __restrict__ psig,
    const float* __restrict__ logp,
    const int* __restrict__ vlist, const int* __restrict__ hlist,
    const int* __restrict__ vcount, const int* __restrict__ hcount,
    float* __restrict__ partials) {
  int q = blockIdx.x, i = blockIdx.y;
  int tid = threadIdx.x, lane = tid & 63, wid = tid >> 6;
  int hc = hcount[i];
  if (hc <= 0) { if (tid == 0) partials[i * Q_ + q] = 0.0f; return; }

  __shared__ __align__(16) float amu[256];
  __shared__ __align__(16) float asg[256];
  __shared__ int nidx[256];
  __shared__ float lgp[20];
  __shared__ float lgt[257];
  __shared__ float wsum[4];

  // key = fold_in(key(42), i); k1,k2,k3 = split (partitionable)
  uint32_t kf0 = 0u, kf1 = (uint32_t)i;
  tf2x32(0u, 42u, kf0, kf1);
  uint32_t k1a = 0u, k1b = 0u; tf2x32(kf0, kf1, k1a, k1b);
  uint32_t k2a = 0u, k2b = 1u; tf2x32(kf0, kf1, k2a, k2b);
  uint32_t k3a = 0u, k3b = 2u; tf2x32(kf0, kf1, k3a, k3b);

  // anchor
  uint32_t ab = tf_xor(k1a, k1b, 0u, (uint32_t)q);
  float ua = fmaxf(0.0f, u01(ab));
  int jq = (int)(ua * (float)hc);
  jq = min(max(jq, 0), hc - 1);
  int a_idx = hlist[i * P_ + jq];
  {
    float rdn_a = rdn[a_idx];
    uint32_t v = feat[(size_t)a_idx * 256 + tid];
    amu[tid] = bf_lo(v) * rdn_a;     // normalized anchor
    asg[tid] = bf_hi(v);
  }
  if (tid < 20) lgp[tid] = logp[i * 20 + tid];
  __syncthreads();

  // negative sampling: thread tid == n. Gumbel-argmax over 20 classes.
  {
    int n = tid;
    uint32_t base = ((uint32_t)q * 256u + (uint32_t)n) * 20u;
    float best = -3.4e38f; int arg = 0;
    for (int t = 0; t < 20; ++t) {
      uint32_t bits = tf_xor(k2a, k2b, 0u, base + (uint32_t)t);
      float f = u01(bits);
      float u = fmaxf(TINY_, f + TINY_);
      float g = -__logf(-__logf(u));
      float sc = g + lgp[t];
      if (sc > best) { best = sc; arg = t; }
    }
    int nseg = (i + 1 + arg) % S_;
    int cnt = vcount[nseg];
    uint32_t b3 = tf_xor(k3a, k3b, 0u, (uint32_t)q * 256u + (uint32_t)n);
    float u3 = fmaxf(0.0f, u01(b3));
    int jp = (int)(u3 * (float)cnt);
    jp = min(max(jp, 0), max(cnt - 1, 0));
    nidx[n] = vlist[nseg * P_ + jp];
  }
  // proto logit (j = 0) from f32 protos: one channel per thread
  {
    float d = amu[tid] - pmn[i * 256 + tid];
    float s = asg[tid] + psig[i * 256 + tid];
    float term = d * d / s + __logf(s);
    for (int off = 32; off > 0; off >>= 1) term += __shfl_xor(term, off, 64);
    if (lane == 0) wsum[wid] = term;
  }
  __syncthreads();
  if (tid == 0) lgt[0] = -(wsum[0] + wsum[1] + wsum[2] + wsum[3]) * (1.0f / 256.0f);

  // 16 lanes per logit; lane t owns uint4 indices {t, 16+t, 32+t, 48+t}
  int t = lane & 15;
  int g = (wid << 2) | (lane >> 4);          // 0..15
  float4 am[4], as4[4];
#pragma unroll
  for (int k = 0; k < 4; ++k) {
    int cb = (k * 16 + t) << 2;
    am[k] = *(const float4*)(amu + cb);
    as4[k] = *(const float4*)(asg + cb);
  }
  for (int iter = 0; iter < 16; ++iter) {
    int j = iter * 16 + g;                   // negative index 0..255
    int rid = nidx[j];
    float rb = rdn[rid];
    const uint32_t* __restrict__ row = feat + (size_t)rid * 256;
    uint4 pv0 = *(const uint4*)(row + ((0 * 16 + t) << 2));
    uint4 pv1 = *(const uint4*)(row + ((1 * 16 + t) << 2));
    uint4 pv2 = *(const uint4*)(row + ((2 * 16 + t) << 2));
    uint4 pv3 = *(const uint4*)(row + ((3 * 16 + t) << 2));
    float acc = 0.0f, pacc = 1.0f;
#define MLS4(pv, k)                                                        \
    {                                                                      \
      float bm0 = bf_lo(pv.x), bs0 = bf_hi(pv.x);                          \
      float bm1 = bf_lo(pv.y), bs1 = bf_hi(pv.y);                          \
      float bm2 = bf_lo(pv.z), bs2 = bf_hi(pv.z);                          \
      float bm3 = bf_lo(pv.w), bs3 = bf_hi(pv.w);                          \
      float d0 = fmaf(bm0, -rb, am[k].x), s0 = as4[k].x + bs0;             \
      float d1 = fmaf(bm1, -rb, am[k].y), s1 = as4[k].y + bs1;             \
      float d2 = fmaf(bm2, -rb, am[k].z), s2 = as4[k].z + bs2;             \
      float d3 = fmaf(bm3, -rb, am[k].w), s3 = as4[k].w + bs3;             \
      acc = fmaf(d0 * d0, __builtin_amdgcn_rcpf(s0), acc);                 \
      acc = fmaf(d1 * d1, __builtin_amdgcn_rcpf(s1), acc);                 \
      acc = fmaf(d2 * d2, __builtin_amdgcn_rcpf(s2), acc);                 \
      acc = fmaf(d3 * d3, __builtin_amdgcn_rcpf(s3), acc);                 \
      pacc *= (s0 * s1) * (s2 * s3);                                       \
    }
    MLS4(pv0, 0) MLS4(pv1, 1) MLS4(pv2, 2) MLS4(pv3, 3)
#undef MLS4
    acc += __logf(pacc);   // product of 16 s in [0.2,2.2]^16: safe in f32
    acc += __shfl_xor(acc, 1, 64);
    acc += __shfl_xor(acc, 2, 64);
    acc += __shfl_xor(acc, 4, 64);
    acc += __shfl_xor(acc, 8, 64);
    if (t == 0) lgt[1 + j] = -acc * (1.0f / 256.0f);
  }
  __syncthreads();

  if (wid == 0) {
    float mx = -3.4e38f;
    for (int j2 = lane; j2 < 257; j2 += 64) mx = fmaxf(mx, lgt[j2]);
    for (int off = 32; off > 0; off >>= 1) mx = fmaxf(mx, __shfl_xor(mx, off, 64));
    float se = 0.0f;
    for (int j2 = lane; j2 < 257; j2 += 64) se += __expf(lgt[j2] - mx);
    for (int off = 32; off > 0; off >>= 1) se += __shfl_xor(se, off, 64);
    if (lane == 0) partials[i * Q_ + q] = __logf(se) + mx - lgt[0];
  }
}

// ---------------- main: slow fallback (NCHW gather, round-4 code) -----------
__global__ __launch_bounds__(256) void k_main_slow(
    const float* __restrict__ mu, const float* __restrict__ sigma,
    const float* __restrict__ denom,
    const float* __restrict__ pmn, const float* __restrict__ psig,
    const float* __restrict__ logp,
    const int* __restrict__ vlist, const int* __restrict__ hlist,
    const int* __restrict__ vcount, const int* __restrict__ hcount,
    float* __restrict__ partials) {
  int q = blockIdx.x, i = blockIdx.y;
  int tid = threadIdx.x, lane = tid & 63, wid = tid >> 6;
  int hc = hcount[i];
  if (hc <= 0) { if (tid == 0) partials[i * Q_ + q] = 0.0f; return; }

  __shared__ __align__(16) float amu[256];
  __shared__ __align__(16) float asg[256];
  __shared__ int nidx[256];
  __shared__ float lgp[20];
  __shared__ float lgt[257];

  uint32_t kf0 = 0u, kf1 = (uint32_t)i;
  tf2x32(0u, 42u, kf0, kf1);
  uint32_t k1a = 0u, k1b = 0u; tf2x32(kf0, kf1, k1a, k1b);
  uint32_t k2a = 0u, k2b = 1u; tf2x32(kf0, kf1, k2a, k2b);
  uint32_t k3a = 0u, k3b = 2u; tf2x32(kf0, kf1, k3a, k3b);

  uint32_t ab = tf_xor(k1a, k1b, 0u, (uint32_t)q);
  float ua = fmaxf(0.0f, u01(ab));
  int jq = (int)(ua * (float)hc);
  jq = min(max(jq, 0), hc - 1);
  int a_idx = hlist[i * P_ + jq];
  {
    int b = a_idx >> 12, hw = a_idx & 4095;
    float rdnv = 1.0f / denom[a_idx];
    size_t base = ((size_t)b << 20) + (size_t)hw + ((size_t)tid << 12);
    amu[tid] = mu[base] * rdnv;
    asg[tid] = sigma[base];
  }
  if (tid < 20) lgp[tid] = logp[i * 20 + tid];
  __syncthreads();

  {
    int n = tid;
    uint32_t base = ((uint32_t)q * 256u + (uint32_t)n) * 20u;
    float best = -3.4e38f; int arg = 0;
    for (int t = 0; t < 20; ++t) {
      uint32_t bits = tf_xor(k2a, k2b, 0u, base + (uint32_t)t);
      float f = u01(bits);
      float u = fmaxf(TINY_, f + TINY_);
      float g = -__logf(-__logf(u));
      float sc = g + lgp[t];
      if (sc > best) { best = sc; arg = t; }
    }
    int nseg = (i + 1 + arg) % S_;
    int cnt = vcount[nseg];
    uint32_t b3 = tf_xor(k3a, k3b, 0u, (uint32_t)q * 256u + (uint32_t)n);
    float u3 = fmaxf(0.0f, u01(b3));
    int jp = (int)(u3 * (float)cnt);
    jp = min(max(jp, 0), max(cnt - 1, 0));
    nidx[n] = vlist[nseg * P_ + jp];
  }
  __syncthreads();

  int c0 = lane * 4;
  float4 am4 = *(const float4*)(amu + c0);
  float4 as4 = *(const float4*)(asg + c0);
  for (int j = wid; j < 257; j += 4) {
    float bm0, bm1, bm2, bm3, bs0, bs1, bs2, bs3;
    if (j == 0) {
      float4 bm4 = *(const float4*)(pmn + i * 256 + c0);
      float4 bs4 = *(const float4*)(psig + i * 256 + c0);
      bm0 = bm4.x; bm1 = bm4.y; bm2 = bm4.z; bm3 = bm4.w;
      bs0 = bs4.x; bs1 = bs4.y; bs2 = bs4.z; bs3 = bs4.w;
    } else {
      int pix = nidx[j - 1];
      int b = pix >> 12, hw = pix & 4095;
      float rdnv = 1.0f / denom[pix];
      size_t base = ((size_t)b << 20) + (size_t)hw + ((size_t)(c0) << 12);
      bm0 = mu[base] * rdnv;          bs0 = sigma[base];
      bm1 = mu[base + 4096] * rdnv;   bs1 = sigma[base + 4096];
      bm2 = mu[base + 8192] * rdnv;   bs2 = sigma[base + 8192];
      bm3 = mu[base + 12288] * rdnv;  bs3 = sigma[base + 12288];
    }
    float d0 = am4.x - bm0, s0 = as4.x + bs0;
    float d1 = am4.y - bm1, s1 = as4.y + bs1;
    float d2 = am4.z - bm2, s2 = as4.z + bs2;
    float d3 = am4.w - bm3, s3 = as4.w + bs3;
    float acc = d0 * d0 / s0 + __logf(s0);
    acc += d1 * d1 / s1 + __logf(s1);
    acc += d2 * d2 / s2 + __logf(s2);
    acc += d3 * d3 / s3 + __logf(s3);
    for (int off = 32; off > 0; off >>= 1) acc += __shfl_xor(acc, off, 64);
    if (lane == 0) lgt[j] = -acc * (1.0f / 256.0f);
  }
  __syncthreads();

  if (wid == 0) {
    float mx = -3.4e38f;
    for (int j = lane; j < 257; j += 64) mx = fmaxf(mx, lgt[j]);
    for (int off = 32; off > 0; off >>= 1) mx = fmaxf(mx, __shfl_xor(mx, off, 64));
    float se = 0.0f;
    for (int j = lane; j < 257; j += 64) se += __expf(lgt[j] - mx);
    for (int off = 32; off > 0; off >>= 1) se += __shfl_xor(se, off, 64);
    if (lane == 0) partials[i * Q_ + q] = __logf(se) + mx - lgt[0];
  }
}

// ---------------- final reduction, dtype-hedged output ----------------------
__global__ __launch_bounds__(256) void k_final(
    const float* __restrict__ partials, const int* __restrict__ vcount,
    const int* __restrict__ hcount, uint32_t* __restrict__ out) {
  __shared__ float ces[S_];
  int tid = threadIdx.x;
  if (tid < S_) {
    float s = 0.0f;
    for (int qq = 0; qq < Q_; ++qq) s += partials[tid * Q_ + qq];
    ces[tid] = (hcount[tid] > 0) ? (s * (1.0f / Q_)) : 0.0f;
  }
  __syncthreads();
  if (tid == 0) {
    float tot = 0.0f, vn = 0.0f;
    for (int s2 = 0; s2 < S_; ++s2) {
      tot += ces[s2];
      if (vcount[s2] > 0) vn += 1.0f;
    }
    float val = tot / vn;
    uint32_t u = __float_as_uint(val);
    uint32_t bf = (u + 0x7FFFu + ((u >> 16) & 1u)) >> 16;
    out[0] = (bf << 16) | bf;
  }
}

extern "C" void kernel_launch(void* const* d_in, const int* in_sizes, int n_in,
                              void* d_out, int out_size, void* d_ws, size_t ws_size,
                              hipStream_t stream) {
  const float* mu    = (const float*)d_in[0];
  const float* sigma = (const float*)d_in[1];
  const float* label = (const float*)d_in[2];
  const float* maskp = (const float*)d_in[3];
  const float* prob  = (const float*)d_in[4];

  char* w = (char*)d_ws;
  size_t off = 0;
  auto alloc = [&](size_t bytes) -> void* {
    off = (off + 255) & ~(size_t)255;
    void* r = w + off;
    off += bytes;
    return r;
  };
  // small buffers (~14 MiB)
  float* denom     = (float*)alloc((size_t)P_ * 4);   // slow path
  float* rdn       = (float*)alloc((size_t)P_ * 4);   // fast path
  int*   segid     = (int*)alloc((size_t)P_ * 4);
  int*   hardf     = (int*)alloc((size_t)P_ * 4);
  int*   vlist     = (int*)alloc((size_t)S_ * P_ * 4);
  int*   hlist     = (int*)alloc((size_t)S_ * P_ * 4);
  int*   vcount    = (int*)alloc(S_ * 4);
  int*   hcount    = (int*)alloc(S_ * 4);
  float* proto_acc = (float*)alloc((size_t)C_ * 42 * 4);
  float* pmn       = (float*)alloc((size_t)S_ * C_ * 4);
  float* psig      = (float*)alloc((size_t)S_ * C_ * 4);
  float* logp      = (float*)alloc((size_t)S_ * 20 * 4);
  float* partials  = (float*)alloc((size_t)S_ * Q_ * 4);
  int*   countsV   = (int*)alloc((size_t)256 * S_ * 4);
  int*   countsH   = (int*)alloc((size_t)256 * S_ * 4);
  int*   offsV     = (int*)alloc((size_t)256 * S_ * 4);
  int*   offsH     = (int*)alloc((size_t)256 * S_ * 4);
  float* ssqp      = (float*)alloc((size_t)4 * P_ * 4);          // 1 MiB
  float* partA     = (float*)alloc((size_t)32 * 10752 * 4);      // 1.4 MiB

  // fast-path big buffers: feat 64 MiB + part 44 MiB
  size_t feat_bytes = (size_t)P_ * 256 * 4;
  size_t part_bytes = (size_t)1024 * 10752 * 4;
  size_t need = ((off + 255) & ~(size_t)255) + feat_bytes + 256 + part_bytes;
  bool fast = (ws_size >= need);
  uint32_t* feat = fast ? (uint32_t*)alloc(feat_bytes) : nullptr;
  float*    part = fast ? (float*)alloc(part_bytes) : nullptr;

  if (fast) {
    k_prep_light<<<P_ / 256, 256, 0, stream>>>(label, maskp, prob, segid, hardf);
    k_count<<<256, 256, 0, stream>>>(segid, hardf, countsV, countsH);
    k_scan<<<1, 64, 0, stream>>>(countsV, countsH, offsV, offsH, vcount, hcount);
    k_scatter<<<256, 256, 0, stream>>>(segid, hardf, offsV, offsH, vlist, hlist);
    k_transpose<<<dim3(P_ / 64, C_ / 64), 256, 0, stream>>>(mu, sigma, segid,
                                                            feat, part, ssqp);
    k_norm_fin<<<P_ / 256, 256, 0, stream>>>(ssqp, rdn);
    k_reduceA<<<dim3(42, 32), 256, 0, stream>>>(part, partA);
    k_reduceB<<<42, 256, 0, stream>>>(partA, proto_acc);
    k_proto_fin<<<S_, 256, 0, stream>>>(proto_acc, pmn, psig);
    k_logp<<<S_, 256, 0, stream>>>(pmn, psig, logp);
    k_main_fast<<<dim3(Q_, S_), 256, 0, stream>>>(feat, rdn, pmn, psig, logp,
                                                  vlist, hlist, vcount, hcount,
                                                  partials);
  } else {
    k_prep<<<P_ / 256, 256, 0, stream>>>(mu, label, maskp, prob, denom, segid, hardf);
    k_count<<<256, 256, 0, stream>>>(segid, hardf, countsV, countsH);
    k_scan<<<1, 64, 0, stream>>>(countsV, countsH, offsV, offsH, vcount, hcount);
    k_scatter<<<256, 256, 0, stream>>>(segid, hardf, offsV, offsH, vlist, hlist);
    k_proto_acc<<<C_, 256, 0, stream>>>(mu, sigma, segid, proto_acc);
    k_proto_fin<<<S_, 256, 0, stream>>>(proto_acc, pmn, psig);
    k_logp<<<S_, 256, 0, stream>>>(pmn, psig, logp);
    k_main_slow<<<dim3(Q_, S_), 256, 0, stream>>>(mu, sigma, denom, pmn, psig, logp,
                                                  vlist, hlist, vcount, hcount,
                                                  partials);
  }
  k_final<<<1, 256, 0, stream>>>(partials, vcount, hcount, (uint32_t*)d_out);
}